// Round 10
// baseline (165.967 us; speedup 1.0000x reference)
//
#include <hip/hip_runtime.h>
#include <hip/hip_fp16.h>

#define N_NODES 50000
#define N_EDGES 800000
#define IN_F    128
#define OUT_F   32
#define HEADS   4
#define EDGE_DIM 8
#define LRELU_ALPHA 0.2f

#define SCAN_BLK 1024
#define N_SCAN_BLKS ((N_NODES + SCAN_BLK - 1) / SCAN_BLK)  // 49

// native clang vector types: accepted by __builtin_nontemporal_load/store
typedef float    floatx4 __attribute__((ext_vector_type(4)));
typedef unsigned uintx4  __attribute__((ext_vector_type(4)));

// round-to-nearest-even f32 -> bf16 (as ushort in low bits)
__device__ __forceinline__ unsigned f2bf(float f) {
  unsigned u = __float_as_uint(f);
  return (u + 0x7fffu + ((u >> 16) & 1u)) >> 16;
}

// ---------------------------------------------------------------------------
// K1: LDS-tiled fp32 GEMM (xt = x·W, bf16-packed out) + fused alpha reduction
// (lean version: no histogram — fusing it cost occupancy, round 9 post-mortem)
// ---------------------------------------------------------------------------
__global__ __launch_bounds__(256) void k_transform(
    const float* __restrict__ x, const float* __restrict__ W,
    const float* __restrict__ a, unsigned* __restrict__ xtb,
    float* __restrict__ alpha_src, float* __restrict__ alpha_dst) {
  __shared__ float sx[64][128];
  const int t = threadIdx.x;
  const int n0 = blockIdx.x * 64;

  // stage x tile (coalesced float4)
#pragma unroll
  for (int r = 0; r < 8; ++r) {
    const int f = r * 256 + t;   // float4 index within 64x128 tile
    const int node = f >> 5;
    const int i4 = (f & 31) * 4;
    const int n = n0 + node;
    float4 v = make_float4(0.f, 0.f, 0.f, 0.f);
    if (n < N_NODES) v = *reinterpret_cast<const float4*>(&x[(size_t)n * 128 + i4]);
    *reinterpret_cast<float4*>(&sx[node][i4]) = v;
  }
  __syncthreads();

  const int lane31 = t & 31;
  const int ng = t >> 5;          // node group 0..7
  const int ho0 = lane31 * 4;     // 4 consecutive output columns
  const int h = ho0 >> 5;
  const int o0 = ho0 & 31;

  float acc[8][4];
#pragma unroll
  for (int nd = 0; nd < 8; ++nd)
#pragma unroll
    for (int j = 0; j < 4; ++j) acc[nd][j] = 0.f;

  const float* __restrict__ wp = W + h * (IN_F * OUT_F) + o0;
#pragma unroll 4
  for (int i = 0; i < IN_F; ++i) {
    const float4 wv = *reinterpret_cast<const float4*>(&wp[i * OUT_F]);
#pragma unroll
    for (int nd = 0; nd < 8; ++nd) {
      const float xv = sx[ng * 8 + nd][i];
      acc[nd][0] = fmaf(xv, wv.x, acc[nd][0]);
      acc[nd][1] = fmaf(xv, wv.y, acc[nd][1]);
      acc[nd][2] = fmaf(xv, wv.z, acc[nd][2]);
      acc[nd][3] = fmaf(xv, wv.w, acc[nd][3]);
    }
  }

  // store xt as packed bf16 (8 B per thread per node)
#pragma unroll
  for (int nd = 0; nd < 8; ++nd) {
    const int n = n0 + ng * 8 + nd;
    if (n < N_NODES) {
      uint2 pk;
      pk.x = f2bf(acc[nd][0]) | (f2bf(acc[nd][1]) << 16);
      pk.y = f2bf(acc[nd][2]) | (f2bf(acc[nd][3]) << 16);
      *reinterpret_cast<uint2*>(&xtb[(size_t)n * 64 + lane31 * 2]) = pk;
    }
  }

  // fused alpha reduction: alpha_*[n,h] = sum_o xt[n,h,o] * a_*[h,o]
  const float4 as4 = *reinterpret_cast<const float4*>(&a[h * 72 + o0]);
  const float4 ad4 = *reinterpret_cast<const float4*>(&a[h * 72 + 32 + o0]);
#pragma unroll
  for (int nd = 0; nd < 8; ++nd) {
    float s = acc[nd][0] * as4.x + acc[nd][1] * as4.y + acc[nd][2] * as4.z +
              acc[nd][3] * as4.w;
    float d = acc[nd][0] * ad4.x + acc[nd][1] * ad4.y + acc[nd][2] * ad4.z +
              acc[nd][3] * ad4.w;
    s += __shfl_xor(s, 1, 64); d += __shfl_xor(d, 1, 64);
    s += __shfl_xor(s, 2, 64); d += __shfl_xor(d, 2, 64);
    s += __shfl_xor(s, 4, 64); d += __shfl_xor(d, 4, 64);
    if ((t & 7) == 0) {
      const int n = n0 + ng * 8 + nd;
      if (n < N_NODES) {
        alpha_src[n * 4 + h] = s;
        alpha_dst[n * 4 + h] = d;
      }
    }
  }
}

// ---------------------------------------------------------------------------
// K2: histogram of dst (standalone — full occupancy, ~8 µs)
// ---------------------------------------------------------------------------
__global__ __launch_bounds__(256) void k_hist(const int* __restrict__ ei,
                                              unsigned* __restrict__ count) {
  const int e = blockIdx.x * blockDim.x + threadIdx.x;
  if (e >= N_EDGES) return;
  atomicAdd(&count[__builtin_nontemporal_load(&ei[N_EDGES + e])], 1u);
}

// ---------------------------------------------------------------------------
// K3a/b/c: hierarchical exclusive scan of count[] -> row_start[]
// k_scan_c also seeds fill[] = rs[] so the scatter atomic returns an
// absolute CSR slot.
// ---------------------------------------------------------------------------
__global__ __launch_bounds__(SCAN_BLK) void k_scan_a(
    const unsigned* __restrict__ cnt, unsigned* __restrict__ rs,
    unsigned* __restrict__ bsum) {
  __shared__ unsigned wpre[16];
  const int t = threadIdx.x;
  const int i = blockIdx.x * SCAN_BLK + t;
  const int lane = t & 63;
  const int wid = t >> 6;
  unsigned v = (i < N_NODES) ? cnt[i] : 0u;
  unsigned incl = v;
#pragma unroll
  for (int off = 1; off < 64; off <<= 1) {
    unsigned n = __shfl_up(incl, off, 64);
    if (lane >= off) incl += n;
  }
  if (lane == 63) wpre[wid] = incl;
  __syncthreads();
  if (t < 16) {
    unsigned wv = wpre[t];
    unsigned wincl = wv;
#pragma unroll
    for (int off = 1; off < 16; off <<= 1) {
      unsigned n = __shfl_up(wincl, off, 64);
      if (t >= off) wincl += n;
    }
    wpre[t] = wincl - wv;  // exclusive wave prefix
    if (t == 15) bsum[blockIdx.x] = wincl;  // block total
  }
  __syncthreads();
  if (i < N_NODES) rs[i] = incl - v + wpre[wid];
}

__global__ __launch_bounds__(64) void k_scan_b(unsigned* __restrict__ bsum,
                                               unsigned* __restrict__ boff) {
  const int t = threadIdx.x;
  unsigned v = (t < N_SCAN_BLKS) ? bsum[t] : 0u;
  unsigned incl = v;
#pragma unroll
  for (int off = 1; off < 64; off <<= 1) {
    unsigned n = __shfl_up(incl, off, 64);
    if (t >= off) incl += n;
  }
  if (t < N_SCAN_BLKS) boff[t] = incl - v;
}

__global__ __launch_bounds__(SCAN_BLK) void k_scan_c(
    unsigned* __restrict__ rs, const unsigned* __restrict__ boff,
    unsigned* __restrict__ fill) {
  const int i = blockIdx.x * SCAN_BLK + threadIdx.x;
  if (i < N_NODES) {
    const unsigned v = rs[i] + boff[i >> 10];
    rs[i] = v;
    fill[i] = v;
  }
  if (i == 0) rs[N_NODES] = N_EDGES;
}

// ---------------------------------------------------------------------------
// K4: scatter edges into CSR slots. One packed 16B entry per edge:
//   {src, fp16x2(s0,s1), fp16x2(s2,s3), 0}
// Non-temporal store: skip L2 allocate (no RFO / partial-line writeback amp).
// ---------------------------------------------------------------------------
__device__ __forceinline__ uintx4 make_entry(
    int e, int src, int dst, const float* __restrict__ ea,
    const float* __restrict__ a, const float* __restrict__ alpha_src,
    const float* __restrict__ alpha_dst) {
  const floatx4 ev0 = __builtin_nontemporal_load(
      reinterpret_cast<const floatx4*>(&ea[(size_t)e * EDGE_DIM]));
  const floatx4 ev1 = __builtin_nontemporal_load(
      reinterpret_cast<const floatx4*>(&ea[(size_t)e * EDGE_DIM + 4]));
  const float4 als = *reinterpret_cast<const float4*>(&alpha_src[src * 4]);
  const float4 ald = *reinterpret_cast<const float4*>(&alpha_dst[dst * 4]);
  const float* alsp = reinterpret_cast<const float*>(&als);
  const float* aldp = reinterpret_cast<const float*>(&ald);
  unsigned sh[4];
#pragma unroll
  for (int h = 0; h < HEADS; ++h) {
    float s = alsp[h] + aldp[h];
    const float* ae = &a[h * 72 + 64];
    s = fmaf(ev0.x, ae[0], s);
    s = fmaf(ev0.y, ae[1], s);
    s = fmaf(ev0.z, ae[2], s);
    s = fmaf(ev0.w, ae[3], s);
    s = fmaf(ev1.x, ae[4], s);
    s = fmaf(ev1.y, ae[5], s);
    s = fmaf(ev1.z, ae[6], s);
    s = fmaf(ev1.w, ae[7], s);
    s = s > 0.f ? s : LRELU_ALPHA * s;
    sh[h] = (unsigned)__half_as_ushort(__float2half(s));
  }
  uintx4 ent;
  ent.x = (unsigned)src;
  ent.y = sh[0] | (sh[1] << 16);
  ent.z = sh[2] | (sh[3] << 16);
  ent.w = 0u;
  return ent;
}

__global__ __launch_bounds__(256) void k_scatter(
    const int* __restrict__ ei, const float* __restrict__ ea,
    const float* __restrict__ a, const float* __restrict__ alpha_src,
    const float* __restrict__ alpha_dst, unsigned* __restrict__ fill,
    uintx4* __restrict__ csr) {
  const int e = blockIdx.x * blockDim.x + threadIdx.x;
  if (e >= N_EDGES) return;
  const int src = __builtin_nontemporal_load(&ei[e]);
  const int dst = __builtin_nontemporal_load(&ei[N_EDGES + e]);
  const unsigned slot = atomicAdd(&fill[dst], 1u);  // absolute CSR slot
  const uintx4 ent = make_entry(e, src, dst, ea, a, alpha_src, alpha_dst);
  __builtin_nontemporal_store(ent, &csr[slot]);
}

// ---------------------------------------------------------------------------
// K5: one wave per dst. Single pass (no max subtraction — algebraically
// identical softmax; scores are O(1) so exp() cannot overflow fp32).
// csr read non-temporally (read-once; keep L2 for xtb gathers).
// ---------------------------------------------------------------------------
__device__ __forceinline__ float ent_score(const uintx4& ent, int hA) {
  const unsigned uu = (hA < 2) ? ent.y : ent.z;
  const unsigned us = (hA & 1) ? (uu >> 16) : (uu & 0xffffu);
  return __half2float(__ushort_as_half((unsigned short)us));
}

__global__ __launch_bounds__(256) void k_agg(
    const unsigned* __restrict__ rs, const uintx4* __restrict__ csr,
    const unsigned* __restrict__ xtb, float* __restrict__ out) {
  const int lane = threadIdx.x & 63;
  const int dst = (int)((blockIdx.x * (unsigned)blockDim.x + threadIdx.x) >> 6);
  if (dst >= N_NODES) return;

  const unsigned j0 = rs[dst];
  const unsigned j1 = rs[dst + 1];
  const int deg = (int)(j1 - j0);

  float a0 = 0.f, a1 = 0.f, lsum = 0.f;

  if (deg > 0) {
    const int rounds = (deg + 15) >> 4;
    const int sub = lane >> 2;   // edge-within-round in score space
    const int hA = lane & 3;     // head in score space
    const int hB = lane >> 4;    // head of this lane's output features

    for (int r = 0; r < rounds; ++r) {
      const int base = (int)j0 + r * 16;
      const int j = base + sub;
      uintx4 ent;
      if (j < (int)j1) {
        ent = __builtin_nontemporal_load(&csr[j]);
      } else {
        ent.x = 0u; ent.y = 0xfc00fc00u; ent.z = 0xfc00fc00u; ent.w = 0u;
      }
      const float w = __expf(ent_score(ent, hA));  // pad: exp(-inf)=0
      lsum += w;
      const int sx = (int)ent.x;
#pragma unroll
      for (int jj = 0; jj < 16; ++jj) {
        const int src = __shfl(sx, 4 * jj, 64);
        const float wj = __shfl(w, 4 * jj + hB, 64);
        const unsigned u = xtb[(size_t)src * 64 + lane];
        a0 = fmaf(wj, __uint_as_float(u << 16), a0);
        a1 = fmaf(wj, __uint_as_float(u & 0xffff0000u), a1);
      }
    }
    lsum += __shfl_xor(lsum, 4, 64);
    lsum += __shfl_xor(lsum, 8, 64);
    lsum += __shfl_xor(lsum, 16, 64);
    lsum += __shfl_xor(lsum, 32, 64);
    lsum = __shfl(lsum, hB, 64);   // lane hB holds head hB's sum
  }

  const float inv = 1.0f / (lsum + 1e-10f);
  out[(size_t)dst * 128 + lane * 2 + 0] = a0 * inv;
  out[(size_t)dst * 128 + lane * 2 + 1] = a1 * inv;
}

extern "C" void kernel_launch(void* const* d_in, const int* in_sizes, int n_in,
                              void* d_out, int out_size, void* d_ws,
                              size_t ws_size, hipStream_t stream) {
  const float* x = (const float*)d_in[0];
  const int* ei = (const int*)d_in[1];
  const float* ea = (const float*)d_in[2];
  const float* W = (const float*)d_in[3];
  const float* a = (const float*)d_in[4];
  float* out = (float*)d_out;

  // workspace layout
  char* p = (char*)d_ws;
  unsigned* xtb = (unsigned*)p;     p += (size_t)N_NODES * 64 * 4;    // 12.8 MB
  uintx4* csr = (uintx4*)p;         p += (size_t)N_EDGES * 16;        // 12.8 MB
  float* alpha_src = (float*)p;     p += (size_t)N_NODES * 4 * 4;     // 0.8 MB
  float* alpha_dst = (float*)p;     p += (size_t)N_NODES * 4 * 4;     // 0.8 MB
  unsigned* count = (unsigned*)p;   p += (size_t)N_NODES * 4;         // 0.2 MB
  unsigned* fill = (unsigned*)p;    p += (size_t)N_NODES * 4;         // 0.2 MB
  unsigned* rs = (unsigned*)p;      p += (size_t)(N_NODES + 1) * 4;
  unsigned* bsum = (unsigned*)p;    p += 64 * 4;
  unsigned* boff = (unsigned*)p;    p += 64 * 4;

  (void)hipMemsetAsync(count, 0, (size_t)N_NODES * 4, stream);

  k_transform<<<(N_NODES + 63) / 64, 256, 0, stream>>>(x, W, a, xtb, alpha_src,
                                                       alpha_dst);
  k_hist<<<(N_EDGES + 255) / 256, 256, 0, stream>>>(ei, count);
  k_scan_a<<<N_SCAN_BLKS, SCAN_BLK, 0, stream>>>(count, rs, bsum);
  k_scan_b<<<1, 64, 0, stream>>>(bsum, boff);
  k_scan_c<<<N_SCAN_BLKS, SCAN_BLK, 0, stream>>>(rs, boff, fill);
  k_scatter<<<(N_EDGES + 255) / 256, 256, 0, stream>>>(
      ei, ea, a, alpha_src, alpha_dst, fill, csr);
  k_agg<<<(N_NODES * 64 + 255) / 256, 256, 0, stream>>>(rs, csr, xtb, out);
}

// Round 11
// 156.013 us; speedup vs baseline: 1.0638x; 1.0638x over previous
//
#include <hip/hip_runtime.h>
#include <hip/hip_fp16.h>

#define N_NODES 50000
#define N_EDGES 800000
#define IN_F    128
#define OUT_F   32
#define HEADS   4
#define EDGE_DIM 8
#define LRELU_ALPHA 0.2f

#define SCAN_BLK 1024
#define N_SCAN_BLKS ((N_NODES + SCAN_BLK - 1) / SCAN_BLK)  // 49
#define HIST_BLKS (N_EDGES / 256)                          // 3125

// native clang vector types
typedef float    floatx4 __attribute__((ext_vector_type(4)));
typedef unsigned uintx4  __attribute__((ext_vector_type(4)));
typedef short    short4v __attribute__((ext_vector_type(4)));
typedef short    short8v __attribute__((ext_vector_type(8)));
typedef float    f32x4   __attribute__((ext_vector_type(4)));

// round-to-nearest-even f32 -> bf16 (as ushort in low bits)
__device__ __forceinline__ unsigned f2bf(float f) {
  unsigned u = __float_as_uint(f);
  return (u + 0x7fffu + ((u >> 16) & 1u)) >> 16;
}

// ---------------------------------------------------------------------------
// K1: MFMA bf16 GEMM. xt[n,ho] = sum_i x[n,i]*W[h,i,o]; 64 nodes/block.
// LDS: x-tile as bf16 [64][136] (pad 8 shorts vs 16-way conflict),
//      W^T as bf16 [128][136]. 4 waves: wave w = M-tile w, all 8 N-tiles.
// mfma_f32_16x16x32_bf16: A row = l&15, k = (l>>4)*8+j (8 contiguous);
// B col = l&15, same k-chunk (W^T storage → contiguous); C/D col=l&15,
// row=(l>>4)*4+reg  [guide §3, m89/m91-verified].
// Epilogue: pack bf16 pairs via shfl_xor(1), even lanes store 4B.
// ---------------------------------------------------------------------------
__global__ __launch_bounds__(256) void k_transform(
    const float* __restrict__ x, const float* __restrict__ W,
    unsigned* __restrict__ xtb) {
  __shared__ short sxb[64][136];
  __shared__ short wt[128][136];
  const int t = threadIdx.x;
  const int n0 = blockIdx.x * 64;

  // stage W -> wt transposed bf16: wt[h*32+o][i] = bf16(W[h,i,o])
#pragma unroll
  for (int r = 0; r < 64; ++r) {
    const int idx = r * 256 + t;         // 0..16383, coalesced read
    const int h = idx >> 12;
    const int i = (idx >> 5) & 127;
    const int o = idx & 31;
    wt[h * 32 + o][i] = (short)f2bf(W[idx]);
  }

  // stage x tile -> bf16 LDS
#pragma unroll
  for (int r = 0; r < 8; ++r) {
    const int f = r * 256 + t;           // float4 index in 64x128 tile
    const int node = f >> 5;
    const int i4 = (f & 31) * 4;
    const int n = n0 + node;
    float4 v = make_float4(0.f, 0.f, 0.f, 0.f);
    if (n < N_NODES) v = *reinterpret_cast<const float4*>(&x[(size_t)n * 128 + i4]);
    short4v s4;
    s4.x = (short)f2bf(v.x);
    s4.y = (short)f2bf(v.y);
    s4.z = (short)f2bf(v.z);
    s4.w = (short)f2bf(v.w);
    *reinterpret_cast<short4v*>(&sxb[node][i4]) = s4;
  }
  __syncthreads();

  const int w = t >> 6;        // wave id = M-tile
  const int lane = t & 63;
  const int r16 = lane & 15;
  const int kg = lane >> 4;    // k-group

  f32x4 acc[8];
#pragma unroll
  for (int nt = 0; nt < 8; ++nt) acc[nt] = (f32x4)(0.f);

#pragma unroll
  for (int kk = 0; kk < 4; ++kk) {
    const short8v afrag =
        *reinterpret_cast<const short8v*>(&sxb[w * 16 + r16][kk * 32 + kg * 8]);
#pragma unroll
    for (int nt = 0; nt < 8; ++nt) {
      const short8v bfrag =
          *reinterpret_cast<const short8v*>(&wt[nt * 16 + r16][kk * 32 + kg * 8]);
      acc[nt] = __builtin_amdgcn_mfma_f32_16x16x32_bf16(afrag, bfrag, acc[nt],
                                                        0, 0, 0);
    }
  }

  // epilogue: C row = kg*4+reg (node), col = r16; pack col pairs
#pragma unroll
  for (int nt = 0; nt < 8; ++nt) {
#pragma unroll
    for (int reg = 0; reg < 4; ++reg) {
      const float v = acc[nt][reg];
      const float vp = __shfl_xor(v, 1, 64);   // partner col
      if (!(lane & 1)) {
        const int node = n0 + w * 16 + kg * 4 + reg;
        if (node < N_NODES) {
          const unsigned u = f2bf(v) | (f2bf(vp) << 16);
          xtb[(size_t)node * 64 + nt * 8 + (r16 >> 1)] = u;
        }
      }
    }
  }
}

// ---------------------------------------------------------------------------
// K2: dst histogram + alpha reduction from xtb.
// 3125 blocks: thread t does 1 edge atomic; thread-quads cover 16 nodes/block,
// thread q of a quad computes head q (head = contiguous 16 uints of xtb row).
// ---------------------------------------------------------------------------
__global__ __launch_bounds__(256) void k_hist_alpha(
    const int* __restrict__ ei, const unsigned* __restrict__ xtb,
    const float* __restrict__ a, unsigned* __restrict__ count,
    float* __restrict__ alpha_src, float* __restrict__ alpha_dst) {
  const int t = threadIdx.x;
  const int e = blockIdx.x * 256 + t;
  atomicAdd(&count[__builtin_nontemporal_load(&ei[N_EDGES + e])], 1u);

  const int node = blockIdx.x * 16 + (t >> 2);
  if (node >= N_NODES) return;
  const int q = t & 3;  // head
  const unsigned* __restrict__ row = &xtb[(size_t)node * 64 + q * 16];
  const float* __restrict__ as = &a[q * 72];
  const float* __restrict__ ad = &a[q * 72 + 32];
  float s = 0.f, d = 0.f;
#pragma unroll
  for (int j = 0; j < 16; ++j) {
    const unsigned u = row[j];
    const float lo = __uint_as_float(u << 16);
    const float hi = __uint_as_float(u & 0xffff0000u);
    s = fmaf(lo, as[2 * j], s);
    s = fmaf(hi, as[2 * j + 1], s);
    d = fmaf(lo, ad[2 * j], d);
    d = fmaf(hi, ad[2 * j + 1], d);
  }
  alpha_src[node * 4 + q] = s;   // coalesced: index == blockbase + t
  alpha_dst[node * 4 + q] = d;
}

// ---------------------------------------------------------------------------
// K3a/b/c: hierarchical exclusive scan of count[] -> row_start[]
// k_scan_c also seeds fill[] = rs[].
// ---------------------------------------------------------------------------
__global__ __launch_bounds__(SCAN_BLK) void k_scan_a(
    const unsigned* __restrict__ cnt, unsigned* __restrict__ rs,
    unsigned* __restrict__ bsum) {
  __shared__ unsigned wpre[16];
  const int t = threadIdx.x;
  const int i = blockIdx.x * SCAN_BLK + t;
  const int lane = t & 63;
  const int wid = t >> 6;
  unsigned v = (i < N_NODES) ? cnt[i] : 0u;
  unsigned incl = v;
#pragma unroll
  for (int off = 1; off < 64; off <<= 1) {
    unsigned n = __shfl_up(incl, off, 64);
    if (lane >= off) incl += n;
  }
  if (lane == 63) wpre[wid] = incl;
  __syncthreads();
  if (t < 16) {
    unsigned wv = wpre[t];
    unsigned wincl = wv;
#pragma unroll
    for (int off = 1; off < 16; off <<= 1) {
      unsigned n = __shfl_up(wincl, off, 64);
      if (t >= off) wincl += n;
    }
    wpre[t] = wincl - wv;
    if (t == 15) bsum[blockIdx.x] = wincl;
  }
  __syncthreads();
  if (i < N_NODES) rs[i] = incl - v + wpre[wid];
}

__global__ __launch_bounds__(64) void k_scan_b(unsigned* __restrict__ bsum,
                                               unsigned* __restrict__ boff) {
  const int t = threadIdx.x;
  unsigned v = (t < N_SCAN_BLKS) ? bsum[t] : 0u;
  unsigned incl = v;
#pragma unroll
  for (int off = 1; off < 64; off <<= 1) {
    unsigned n = __shfl_up(incl, off, 64);
    if (t >= off) incl += n;
  }
  if (t < N_SCAN_BLKS) boff[t] = incl - v;
}

__global__ __launch_bounds__(SCAN_BLK) void k_scan_c(
    unsigned* __restrict__ rs, const unsigned* __restrict__ boff,
    unsigned* __restrict__ fill) {
  const int i = blockIdx.x * SCAN_BLK + threadIdx.x;
  if (i < N_NODES) {
    const unsigned v = rs[i] + boff[i >> 10];
    rs[i] = v;
    fill[i] = v;
  }
  if (i == 0) rs[N_NODES] = N_EDGES;
}

// ---------------------------------------------------------------------------
// K4: scatter edges into CSR slots. Packed 16B entry per edge:
//   {src, fp16x2(s0,s1), fp16x2(s2,s3), 0}; NT loads/stores.
// ---------------------------------------------------------------------------
__device__ __forceinline__ uintx4 make_entry(
    int e, int src, int dst, const float* __restrict__ ea,
    const float* __restrict__ a, const float* __restrict__ alpha_src,
    const float* __restrict__ alpha_dst) {
  const floatx4 ev0 = __builtin_nontemporal_load(
      reinterpret_cast<const floatx4*>(&ea[(size_t)e * EDGE_DIM]));
  const floatx4 ev1 = __builtin_nontemporal_load(
      reinterpret_cast<const floatx4*>(&ea[(size_t)e * EDGE_DIM + 4]));
  const float4 als = *reinterpret_cast<const float4*>(&alpha_src[src * 4]);
  const float4 ald = *reinterpret_cast<const float4*>(&alpha_dst[dst * 4]);
  const float* alsp = reinterpret_cast<const float*>(&als);
  const float* aldp = reinterpret_cast<const float*>(&ald);
  unsigned sh[4];
#pragma unroll
  for (int h = 0; h < HEADS; ++h) {
    float s = alsp[h] + aldp[h];
    const float* ae = &a[h * 72 + 64];
    s = fmaf(ev0.x, ae[0], s);
    s = fmaf(ev0.y, ae[1], s);
    s = fmaf(ev0.z, ae[2], s);
    s = fmaf(ev0.w, ae[3], s);
    s = fmaf(ev1.x, ae[4], s);
    s = fmaf(ev1.y, ae[5], s);
    s = fmaf(ev1.z, ae[6], s);
    s = fmaf(ev1.w, ae[7], s);
    s = s > 0.f ? s : LRELU_ALPHA * s;
    sh[h] = (unsigned)__half_as_ushort(__float2half(s));
  }
  uintx4 ent;
  ent.x = (unsigned)src;
  ent.y = sh[0] | (sh[1] << 16);
  ent.z = sh[2] | (sh[3] << 16);
  ent.w = 0u;
  return ent;
}

__global__ __launch_bounds__(256) void k_scatter(
    const int* __restrict__ ei, const float* __restrict__ ea,
    const float* __restrict__ a, const float* __restrict__ alpha_src,
    const float* __restrict__ alpha_dst, unsigned* __restrict__ fill,
    uintx4* __restrict__ csr) {
  const int e = blockIdx.x * blockDim.x + threadIdx.x;
  if (e >= N_EDGES) return;
  const int src = __builtin_nontemporal_load(&ei[e]);
  const int dst = __builtin_nontemporal_load(&ei[N_EDGES + e]);
  const unsigned slot = atomicAdd(&fill[dst], 1u);  // absolute CSR slot
  const uintx4 ent = make_entry(e, src, dst, ea, a, alpha_src, alpha_dst);
  __builtin_nontemporal_store(ent, &csr[slot]);
}

// ---------------------------------------------------------------------------
// K5: one wave per dst; single-pass softmax (no max subtraction), batched
// 16-wide gather with shfl-broadcast weights/srcs.
// ---------------------------------------------------------------------------
__device__ __forceinline__ float ent_score(const uintx4& ent, int hA) {
  const unsigned uu = (hA < 2) ? ent.y : ent.z;
  const unsigned us = (hA & 1) ? (uu >> 16) : (uu & 0xffffu);
  return __half2float(__ushort_as_half((unsigned short)us));
}

__global__ __launch_bounds__(256) void k_agg(
    const unsigned* __restrict__ rs, const uintx4* __restrict__ csr,
    const unsigned* __restrict__ xtb, float* __restrict__ out) {
  const int lane = threadIdx.x & 63;
  const int dst = (int)((blockIdx.x * (unsigned)blockDim.x + threadIdx.x) >> 6);
  if (dst >= N_NODES) return;

  const unsigned j0 = rs[dst];
  const unsigned j1 = rs[dst + 1];
  const int deg = (int)(j1 - j0);

  float a0 = 0.f, a1 = 0.f, lsum = 0.f;

  if (deg > 0) {
    const int rounds = (deg + 15) >> 4;
    const int sub = lane >> 2;
    const int hA = lane & 3;
    const int hB = lane >> 4;

    for (int r = 0; r < rounds; ++r) {
      const int base = (int)j0 + r * 16;
      const int j = base + sub;
      uintx4 ent;
      if (j < (int)j1) {
        ent = __builtin_nontemporal_load(&csr[j]);
      } else {
        ent.x = 0u; ent.y = 0xfc00fc00u; ent.z = 0xfc00fc00u; ent.w = 0u;
      }
      const float w = __expf(ent_score(ent, hA));  // pad: exp(-inf)=0
      lsum += w;
      const int sx = (int)ent.x;
#pragma unroll
      for (int jj = 0; jj < 16; ++jj) {
        const int src = __shfl(sx, 4 * jj, 64);
        const float wj = __shfl(w, 4 * jj + hB, 64);
        const unsigned u = xtb[(size_t)src * 64 + lane];
        a0 = fmaf(wj, __uint_as_float(u << 16), a0);
        a1 = fmaf(wj, __uint_as_float(u & 0xffff0000u), a1);
      }
    }
    lsum += __shfl_xor(lsum, 4, 64);
    lsum += __shfl_xor(lsum, 8, 64);
    lsum += __shfl_xor(lsum, 16, 64);
    lsum += __shfl_xor(lsum, 32, 64);
    lsum = __shfl(lsum, hB, 64);
  }

  const float inv = 1.0f / (lsum + 1e-10f);
  out[(size_t)dst * 128 + lane * 2 + 0] = a0 * inv;
  out[(size_t)dst * 128 + lane * 2 + 1] = a1 * inv;
}

extern "C" void kernel_launch(void* const* d_in, const int* in_sizes, int n_in,
                              void* d_out, int out_size, void* d_ws,
                              size_t ws_size, hipStream_t stream) {
  const float* x = (const float*)d_in[0];
  const int* ei = (const int*)d_in[1];
  const float* ea = (const float*)d_in[2];
  const float* W = (const float*)d_in[3];
  const float* a = (const float*)d_in[4];
  float* out = (float*)d_out;

  // workspace layout
  char* p = (char*)d_ws;
  unsigned* xtb = (unsigned*)p;     p += (size_t)N_NODES * 64 * 4;    // 12.8 MB
  uintx4* csr = (uintx4*)p;         p += (size_t)N_EDGES * 16;        // 12.8 MB
  float* alpha_src = (float*)p;     p += (size_t)N_NODES * 4 * 4;     // 0.8 MB
  float* alpha_dst = (float*)p;     p += (size_t)N_NODES * 4 * 4;     // 0.8 MB
  unsigned* count = (unsigned*)p;   p += (size_t)N_NODES * 4;         // 0.2 MB
  unsigned* fill = (unsigned*)p;    p += (size_t)N_NODES * 4;         // 0.2 MB
  unsigned* rs = (unsigned*)p;      p += (size_t)(N_NODES + 1) * 4;
  unsigned* bsum = (unsigned*)p;    p += 64 * 4;
  unsigned* boff = (unsigned*)p;    p += 64 * 4;

  (void)hipMemsetAsync(count, 0, (size_t)N_NODES * 4, stream);

  k_transform<<<(N_NODES + 63) / 64, 256, 0, stream>>>(x, W, xtb);
  k_hist_alpha<<<HIST_BLKS, 256, 0, stream>>>(ei, xtb, a, count, alpha_src,
                                              alpha_dst);
  k_scan_a<<<N_SCAN_BLKS, SCAN_BLK, 0, stream>>>(count, rs, bsum);
  k_scan_b<<<1, 64, 0, stream>>>(bsum, boff);
  k_scan_c<<<N_SCAN_BLKS, SCAN_BLK, 0, stream>>>(rs, boff, fill);
  k_scatter<<<(N_EDGES + 255) / 256, 256, 0, stream>>>(
      ei, ea, a, alpha_src, alpha_dst, fill, csr);
  k_agg<<<(N_NODES * 64 + 255) / 256, 256, 0, stream>>>(rs, csr, xtb, out);
}

// Round 12
// 155.977 us; speedup vs baseline: 1.0640x; 1.0002x over previous
//
#include <hip/hip_runtime.h>
#include <hip/hip_fp16.h>

#define N_NODES 50000
#define N_EDGES 800000
#define IN_F    128
#define OUT_F   32
#define HEADS   4
#define EDGE_DIM 8
#define LRELU_ALPHA 0.2f

#define SCAN_BLK 1024
#define N_SCAN_BLKS ((N_NODES + SCAN_BLK - 1) / SCAN_BLK)  // 49
#define HIST_BLKS (N_EDGES / 256)                          // 3125

#define EPB 2048                      // edges per binsort block
#define EPT 8                         // edges per thread (256 thr)
#define NBUCK 98                      // buckets of 512 nodes (dst>>9)
#define NBLK_A ((N_EDGES + EPB - 1) / EPB)  // 391
#define NODES_PER_BUCK 512

// native clang vector types
typedef float    floatx4 __attribute__((ext_vector_type(4)));
typedef unsigned uintx4  __attribute__((ext_vector_type(4)));
typedef short    short4v __attribute__((ext_vector_type(4)));
typedef short    short8v __attribute__((ext_vector_type(8)));
typedef float    f32x4   __attribute__((ext_vector_type(4)));

// round-to-nearest-even f32 -> bf16 (as ushort in low bits)
__device__ __forceinline__ unsigned f2bf(float f) {
  unsigned u = __float_as_uint(f);
  return (u + 0x7fffu + ((u >> 16) & 1u)) >> 16;
}

// ---------------------------------------------------------------------------
// K1: MFMA bf16 GEMM. xt[n,ho] = sum_i x[n,i]*W[h,i,o]; 64 nodes/block.
// (unchanged from round 11)
// ---------------------------------------------------------------------------
__global__ __launch_bounds__(256) void k_transform(
    const float* __restrict__ x, const float* __restrict__ W,
    unsigned* __restrict__ xtb) {
  __shared__ short sxb[64][136];
  __shared__ short wt[128][136];
  const int t = threadIdx.x;
  const int n0 = blockIdx.x * 64;

#pragma unroll
  for (int r = 0; r < 64; ++r) {
    const int idx = r * 256 + t;
    const int h = idx >> 12;
    const int i = (idx >> 5) & 127;
    const int o = idx & 31;
    wt[h * 32 + o][i] = (short)f2bf(W[idx]);
  }

#pragma unroll
  for (int r = 0; r < 8; ++r) {
    const int f = r * 256 + t;
    const int node = f >> 5;
    const int i4 = (f & 31) * 4;
    const int n = n0 + node;
    float4 v = make_float4(0.f, 0.f, 0.f, 0.f);
    if (n < N_NODES) v = *reinterpret_cast<const float4*>(&x[(size_t)n * 128 + i4]);
    short4v s4;
    s4.x = (short)f2bf(v.x);
    s4.y = (short)f2bf(v.y);
    s4.z = (short)f2bf(v.z);
    s4.w = (short)f2bf(v.w);
    *reinterpret_cast<short4v*>(&sxb[node][i4]) = s4;
  }
  __syncthreads();

  const int w = t >> 6;
  const int lane = t & 63;
  const int r16 = lane & 15;
  const int kg = lane >> 4;

  f32x4 acc[8];
#pragma unroll
  for (int nt = 0; nt < 8; ++nt) acc[nt] = (f32x4)(0.f);

#pragma unroll
  for (int kk = 0; kk < 4; ++kk) {
    const short8v afrag =
        *reinterpret_cast<const short8v*>(&sxb[w * 16 + r16][kk * 32 + kg * 8]);
#pragma unroll
    for (int nt = 0; nt < 8; ++nt) {
      const short8v bfrag =
          *reinterpret_cast<const short8v*>(&wt[nt * 16 + r16][kk * 32 + kg * 8]);
      acc[nt] = __builtin_amdgcn_mfma_f32_16x16x32_bf16(afrag, bfrag, acc[nt],
                                                        0, 0, 0);
    }
  }

#pragma unroll
  for (int nt = 0; nt < 8; ++nt) {
#pragma unroll
    for (int reg = 0; reg < 4; ++reg) {
      const float v = acc[nt][reg];
      const float vp = __shfl_xor(v, 1, 64);
      if (!(lane & 1)) {
        const int node = n0 + w * 16 + kg * 4 + reg;
        if (node < N_NODES) {
          const unsigned u = f2bf(v) | (f2bf(vp) << 16);
          xtb[(size_t)node * 64 + nt * 8 + (r16 >> 1)] = u;
        }
      }
    }
  }
}

// ---------------------------------------------------------------------------
// K2: dst histogram + alpha reduction from xtb. (unchanged)
// ---------------------------------------------------------------------------
__global__ __launch_bounds__(256) void k_hist_alpha(
    const int* __restrict__ ei, const unsigned* __restrict__ xtb,
    const float* __restrict__ a, unsigned* __restrict__ count,
    float* __restrict__ alpha_src, float* __restrict__ alpha_dst) {
  const int t = threadIdx.x;
  const int e = blockIdx.x * 256 + t;
  atomicAdd(&count[__builtin_nontemporal_load(&ei[N_EDGES + e])], 1u);

  const int node = blockIdx.x * 16 + (t >> 2);
  if (node >= N_NODES) return;
  const int q = t & 3;
  const unsigned* __restrict__ row = &xtb[(size_t)node * 64 + q * 16];
  const float* __restrict__ as = &a[q * 72];
  const float* __restrict__ ad = &a[q * 72 + 32];
  float s = 0.f, d = 0.f;
#pragma unroll
  for (int j = 0; j < 16; ++j) {
    const unsigned u = row[j];
    const float lo = __uint_as_float(u << 16);
    const float hi = __uint_as_float(u & 0xffff0000u);
    s = fmaf(lo, as[2 * j], s);
    s = fmaf(hi, as[2 * j + 1], s);
    d = fmaf(lo, ad[2 * j], d);
    d = fmaf(hi, ad[2 * j + 1], d);
  }
  alpha_src[node * 4 + q] = s;
  alpha_dst[node * 4 + q] = d;
}

// ---------------------------------------------------------------------------
// K3a/b/c: hierarchical exclusive scan of count[] -> row_start[]
// k_scan_c seeds bfill[b] = rs[b*512] (bucket staging cursors).
// ---------------------------------------------------------------------------
__global__ __launch_bounds__(SCAN_BLK) void k_scan_a(
    const unsigned* __restrict__ cnt, unsigned* __restrict__ rs,
    unsigned* __restrict__ bsum) {
  __shared__ unsigned wpre[16];
  const int t = threadIdx.x;
  const int i = blockIdx.x * SCAN_BLK + t;
  const int lane = t & 63;
  const int wid = t >> 6;
  unsigned v = (i < N_NODES) ? cnt[i] : 0u;
  unsigned incl = v;
#pragma unroll
  for (int off = 1; off < 64; off <<= 1) {
    unsigned n = __shfl_up(incl, off, 64);
    if (lane >= off) incl += n;
  }
  if (lane == 63) wpre[wid] = incl;
  __syncthreads();
  if (t < 16) {
    unsigned wv = wpre[t];
    unsigned wincl = wv;
#pragma unroll
    for (int off = 1; off < 16; off <<= 1) {
      unsigned n = __shfl_up(wincl, off, 64);
      if (t >= off) wincl += n;
    }
    wpre[t] = wincl - wv;
    if (t == 15) bsum[blockIdx.x] = wincl;
  }
  __syncthreads();
  if (i < N_NODES) rs[i] = incl - v + wpre[wid];
}

__global__ __launch_bounds__(64) void k_scan_b(unsigned* __restrict__ bsum,
                                               unsigned* __restrict__ boff) {
  const int t = threadIdx.x;
  unsigned v = (t < N_SCAN_BLKS) ? bsum[t] : 0u;
  unsigned incl = v;
#pragma unroll
  for (int off = 1; off < 64; off <<= 1) {
    unsigned n = __shfl_up(incl, off, 64);
    if (t >= off) incl += n;
  }
  if (t < N_SCAN_BLKS) boff[t] = incl - v;
}

__global__ __launch_bounds__(SCAN_BLK) void k_scan_c(
    unsigned* __restrict__ rs, const unsigned* __restrict__ boff,
    unsigned* __restrict__ bfill) {
  const int i = blockIdx.x * SCAN_BLK + threadIdx.x;
  if (i < N_NODES) {
    const unsigned v = rs[i] + boff[i >> 10];
    rs[i] = v;
    if ((i & 511) == 0) bfill[i >> 9] = v;   // bucket staging cursor
  }
  if (i == 0) rs[N_NODES] = N_EDGES;
}

// ---------------------------------------------------------------------------
// entry builder: {src, fp16x2(s0,s1), fp16x2(s2,s3), dst}
// ---------------------------------------------------------------------------
__device__ __forceinline__ uintx4 make_entry(
    int e, int src, int dst, const float* __restrict__ ea,
    const float* __restrict__ a, const float* __restrict__ alpha_src,
    const float* __restrict__ alpha_dst) {
  const floatx4 ev0 = __builtin_nontemporal_load(
      reinterpret_cast<const floatx4*>(&ea[(size_t)e * EDGE_DIM]));
  const floatx4 ev1 = __builtin_nontemporal_load(
      reinterpret_cast<const floatx4*>(&ea[(size_t)e * EDGE_DIM + 4]));
  const float4 als = *reinterpret_cast<const float4*>(&alpha_src[src * 4]);
  const float4 ald = *reinterpret_cast<const float4*>(&alpha_dst[dst * 4]);
  const float* alsp = reinterpret_cast<const float*>(&als);
  const float* aldp = reinterpret_cast<const float*>(&ald);
  unsigned sh[4];
#pragma unroll
  for (int h = 0; h < HEADS; ++h) {
    float s = alsp[h] + aldp[h];
    const float* ae = &a[h * 72 + 64];
    s = fmaf(ev0.x, ae[0], s);
    s = fmaf(ev0.y, ae[1], s);
    s = fmaf(ev0.z, ae[2], s);
    s = fmaf(ev0.w, ae[3], s);
    s = fmaf(ev1.x, ae[4], s);
    s = fmaf(ev1.y, ae[5], s);
    s = fmaf(ev1.z, ae[6], s);
    s = fmaf(ev1.w, ae[7], s);
    s = s > 0.f ? s : LRELU_ALPHA * s;
    sh[h] = (unsigned)__half_as_ushort(__float2half(s));
  }
  uintx4 ent;
  ent.x = (unsigned)src;
  ent.y = sh[0] | (sh[1] << 16);
  ent.z = sh[2] | (sh[3] << 16);
  ent.w = (unsigned)dst;
  return ent;
}

// ---------------------------------------------------------------------------
// K4a: bucket binsort. Per 2048-edge block: entries -> LDS hist by dst>>9 ->
// one global ticket per bucket (contiguous run reservation) -> LDS reorder ->
// coalesced full-line run writes into bucket-staging (= final CSR layout at
// bucket granularity, unordered within bucket).
// ---------------------------------------------------------------------------
__global__ __launch_bounds__(256) void k_binsort(
    const int* __restrict__ ei, const float* __restrict__ ea,
    const float* __restrict__ a, const float* __restrict__ alpha_src,
    const float* __restrict__ alpha_dst, unsigned* __restrict__ bfill,
    uintx4* __restrict__ stage) {
  __shared__ uintx4 sent[EPB];
  __shared__ unsigned short sbk[EPB];
  __shared__ unsigned lhist[128];
  __shared__ unsigned lscan[128];
  __shared__ unsigned gb[128];
  const int t = threadIdx.x;
  const int e0 = blockIdx.x * EPB;
  const int nvalid = min(EPB, N_EDGES - e0);

  if (t < 128) lhist[t] = 0u;
  __syncthreads();

  uintx4 ent[EPT];
  int bk[EPT];
  int lpos[EPT];
#pragma unroll
  for (int k = 0; k < EPT; ++k) {
    const int e = e0 + k * 256 + t;
    bk[k] = -1;
    if (e < N_EDGES) {
      const int src = __builtin_nontemporal_load(&ei[e]);
      const int dst = __builtin_nontemporal_load(&ei[N_EDGES + e]);
      ent[k] = make_entry(e, src, dst, ea, a, alpha_src, alpha_dst);
      bk[k] = dst >> 9;
      lpos[k] = (int)atomicAdd(&lhist[bk[k]], 1u);
    }
  }
  __syncthreads();

  // inclusive Hillis-Steele scan of lhist over 128 slots
  if (t < 128) lscan[t] = lhist[t];
  __syncthreads();
#pragma unroll
  for (int off = 1; off < 128; off <<= 1) {
    unsigned v = 0u;
    if (t < 128 && t >= off) v = lscan[t - off];
    __syncthreads();
    if (t < 128) lscan[t] += v;
    __syncthreads();
  }
  // make exclusive + reserve global runs
  if (t < NBUCK) {
    const unsigned cnt = lhist[t];
    lscan[t] -= cnt;
    gb[t] = cnt ? atomicAdd(&bfill[t], cnt) : 0u;
  }
  __syncthreads();

  // reorder into LDS (bucket-sorted)
#pragma unroll
  for (int k = 0; k < EPT; ++k) {
    if (bk[k] >= 0) {
      const int p = (int)lscan[bk[k]] + lpos[k];
      sent[p] = ent[k];
      sbk[p] = (unsigned short)bk[k];
    }
  }
  __syncthreads();

  // coalesced run writes: consecutive p -> consecutive global addrs
#pragma unroll
  for (int k = 0; k < EPT; ++k) {
    const int p = k * 256 + t;
    if (p < nvalid) {
      const int b = sbk[p];
      stage[gb[b] + (unsigned)(p - (int)lscan[b])] = sent[p];
    }
  }
}

// ---------------------------------------------------------------------------
// K4b: place. Block b owns bucket b (512 nodes, contiguous CSR range).
// LDS fill counters seeded from rs; stream staged entries (coalesced NT
// reads), place at exact slot (random only within block-exclusive 128KB,
// L2-local -> full-line writebacks).
// ---------------------------------------------------------------------------
__global__ __launch_bounds__(1024) void k_place(
    const unsigned* __restrict__ rs, const uintx4* __restrict__ stage,
    uintx4* __restrict__ csr) {
  __shared__ unsigned lfill[NODES_PER_BUCK];
  const int b = blockIdx.x;
  const int node0 = b << 9;
  const int nn = min(NODES_PER_BUCK, N_NODES - node0);
  const int t = threadIdx.x;
  if (t < nn) lfill[t] = rs[node0 + t];
  __syncthreads();
  const unsigned j0 = rs[node0];
  const unsigned j1 = rs[min(node0 + NODES_PER_BUCK, N_NODES)];
  for (unsigned i = j0 + t; i < j1; i += 1024) {
    const uintx4 ent = __builtin_nontemporal_load(&stage[i]);
    const int dst = (int)ent.w;
    const unsigned slot = atomicAdd(&lfill[dst - node0], 1u);
    csr[slot] = ent;
  }
}

// ---------------------------------------------------------------------------
// K5: one wave per dst; single-pass softmax, batched 16-wide gather.
// (unchanged; ent.w ignored)
// ---------------------------------------------------------------------------
__device__ __forceinline__ float ent_score(const uintx4& ent, int hA) {
  const unsigned uu = (hA < 2) ? ent.y : ent.z;
  const unsigned us = (hA & 1) ? (uu >> 16) : (uu & 0xffffu);
  return __half2float(__ushort_as_half((unsigned short)us));
}

__global__ __launch_bounds__(256) void k_agg(
    const unsigned* __restrict__ rs, const uintx4* __restrict__ csr,
    const unsigned* __restrict__ xtb, float* __restrict__ out) {
  const int lane = threadIdx.x & 63;
  const int dst = (int)((blockIdx.x * (unsigned)blockDim.x + threadIdx.x) >> 6);
  if (dst >= N_NODES) return;

  const unsigned j0 = rs[dst];
  const unsigned j1 = rs[dst + 1];
  const int deg = (int)(j1 - j0);

  float a0 = 0.f, a1 = 0.f, lsum = 0.f;

  if (deg > 0) {
    const int rounds = (deg + 15) >> 4;
    const int sub = lane >> 2;
    const int hA = lane & 3;
    const int hB = lane >> 4;

    for (int r = 0; r < rounds; ++r) {
      const int base = (int)j0 + r * 16;
      const int j = base + sub;
      uintx4 ent;
      if (j < (int)j1) {
        ent = __builtin_nontemporal_load(&csr[j]);
      } else {
        ent.x = 0u; ent.y = 0xfc00fc00u; ent.z = 0xfc00fc00u; ent.w = 0u;
      }
      const float w = __expf(ent_score(ent, hA));  // pad: exp(-inf)=0
      lsum += w;
      const int sx = (int)ent.x;
#pragma unroll
      for (int jj = 0; jj < 16; ++jj) {
        const int src = __shfl(sx, 4 * jj, 64);
        const float wj = __shfl(w, 4 * jj + hB, 64);
        const unsigned u = xtb[(size_t)src * 64 + lane];
        a0 = fmaf(wj, __uint_as_float(u << 16), a0);
        a1 = fmaf(wj, __uint_as_float(u & 0xffff0000u), a1);
      }
    }
    lsum += __shfl_xor(lsum, 4, 64);
    lsum += __shfl_xor(lsum, 8, 64);
    lsum += __shfl_xor(lsum, 16, 64);
    lsum += __shfl_xor(lsum, 32, 64);
    lsum = __shfl(lsum, hB, 64);
  }

  const float inv = 1.0f / (lsum + 1e-10f);
  out[(size_t)dst * 128 + lane * 2 + 0] = a0 * inv;
  out[(size_t)dst * 128 + lane * 2 + 1] = a1 * inv;
}

extern "C" void kernel_launch(void* const* d_in, const int* in_sizes, int n_in,
                              void* d_out, int out_size, void* d_ws,
                              size_t ws_size, hipStream_t stream) {
  const float* x = (const float*)d_in[0];
  const int* ei = (const int*)d_in[1];
  const float* ea = (const float*)d_in[2];
  const float* W = (const float*)d_in[3];
  const float* a = (const float*)d_in[4];
  float* out = (float*)d_out;

  // workspace layout
  char* p = (char*)d_ws;
  unsigned* xtb = (unsigned*)p;     p += (size_t)N_NODES * 64 * 4;    // 12.8 MB
  uintx4* csr = (uintx4*)p;         p += (size_t)N_EDGES * 16;        // 12.8 MB
  uintx4* stage = (uintx4*)p;       p += (size_t)N_EDGES * 16;        // 12.8 MB
  float* alpha_src = (float*)p;     p += (size_t)N_NODES * 4 * 4;     // 0.8 MB
  float* alpha_dst = (float*)p;     p += (size_t)N_NODES * 4 * 4;     // 0.8 MB
  unsigned* count = (unsigned*)p;   p += (size_t)N_NODES * 4;         // 0.2 MB
  unsigned* rs = (unsigned*)p;      p += (size_t)(N_NODES + 1) * 4;
  unsigned* bfill = (unsigned*)p;   p += 128 * 4;
  unsigned* bsum = (unsigned*)p;    p += 64 * 4;
  unsigned* boff = (unsigned*)p;    p += 64 * 4;

  (void)hipMemsetAsync(count, 0, (size_t)N_NODES * 4, stream);

  k_transform<<<(N_NODES + 63) / 64, 256, 0, stream>>>(x, W, xtb);
  k_hist_alpha<<<HIST_BLKS, 256, 0, stream>>>(ei, xtb, a, count, alpha_src,
                                              alpha_dst);
  k_scan_a<<<N_SCAN_BLKS, SCAN_BLK, 0, stream>>>(count, rs, bsum);
  k_scan_b<<<1, 64, 0, stream>>>(bsum, boff);
  k_scan_c<<<N_SCAN_BLKS, SCAN_BLK, 0, stream>>>(rs, boff, bfill);
  k_binsort<<<NBLK_A, 256, 0, stream>>>(ei, ea, a, alpha_src, alpha_dst, bfill,
                                        stage);
  k_place<<<NBUCK, 1024, 0, stream>>>(rs, stage, csr);
  k_agg<<<(N_NODES * 64 + 255) / 256, 256, 0, stream>>>(rs, csr, xtb, out);
}

// Round 13
// 149.948 us; speedup vs baseline: 1.1068x; 1.0402x over previous
//
#include <hip/hip_runtime.h>
#include <hip/hip_fp16.h>

#define N_NODES 50000
#define N_EDGES 800000
#define IN_F    128
#define OUT_F   32
#define HEADS   4
#define EDGE_DIM 8
#define LRELU_ALPHA 0.2f

#define SCAN_BLK 1024
#define N_SCAN_BLKS ((N_NODES + SCAN_BLK - 1) / SCAN_BLK)  // 49
#define HIST_BLKS (N_EDGES / 256)                          // 3125

#define EPB 2048                      // edges per binsort block
#define BT  1024                      // binsort threads
#define EPT (EPB / BT)                // 2 edges per thread
#define NBUCK 98                      // buckets of 512 nodes (dst>>9)
#define NBLK_A ((N_EDGES + EPB - 1) / EPB)  // 391
#define NODES_PER_BUCK 512

// native clang vector types
typedef float    floatx4 __attribute__((ext_vector_type(4)));
typedef unsigned uintx4  __attribute__((ext_vector_type(4)));
typedef short    short4v __attribute__((ext_vector_type(4)));
typedef short    short8v __attribute__((ext_vector_type(8)));
typedef float    f32x4   __attribute__((ext_vector_type(4)));

// round-to-nearest-even f32 -> bf16 (as ushort in low bits)
__device__ __forceinline__ unsigned f2bf(float f) {
  unsigned u = __float_as_uint(f);
  return (u + 0x7fffu + ((u >> 16) & 1u)) >> 16;
}

// ---------------------------------------------------------------------------
// K1: MFMA bf16 GEMM. xt[n,ho] = sum_i x[n,i]*W[h,i,o]; 64 nodes/block.
// ---------------------------------------------------------------------------
__global__ __launch_bounds__(256) void k_transform(
    const float* __restrict__ x, const float* __restrict__ W,
    unsigned* __restrict__ xtb) {
  __shared__ short sxb[64][136];
  __shared__ short wt[128][136];
  const int t = threadIdx.x;
  const int n0 = blockIdx.x * 64;

#pragma unroll
  for (int r = 0; r < 64; ++r) {
    const int idx = r * 256 + t;
    const int h = idx >> 12;
    const int i = (idx >> 5) & 127;
    const int o = idx & 31;
    wt[h * 32 + o][i] = (short)f2bf(W[idx]);
  }

#pragma unroll
  for (int r = 0; r < 8; ++r) {
    const int f = r * 256 + t;
    const int node = f >> 5;
    const int i4 = (f & 31) * 4;
    const int n = n0 + node;
    float4 v = make_float4(0.f, 0.f, 0.f, 0.f);
    if (n < N_NODES) v = *reinterpret_cast<const float4*>(&x[(size_t)n * 128 + i4]);
    short4v s4;
    s4.x = (short)f2bf(v.x);
    s4.y = (short)f2bf(v.y);
    s4.z = (short)f2bf(v.z);
    s4.w = (short)f2bf(v.w);
    *reinterpret_cast<short4v*>(&sxb[node][i4]) = s4;
  }
  __syncthreads();

  const int w = t >> 6;
  const int lane = t & 63;
  const int r16 = lane & 15;
  const int kg = lane >> 4;

  f32x4 acc[8];
#pragma unroll
  for (int nt = 0; nt < 8; ++nt) acc[nt] = (f32x4)(0.f);

#pragma unroll
  for (int kk = 0; kk < 4; ++kk) {
    const short8v afrag =
        *reinterpret_cast<const short8v*>(&sxb[w * 16 + r16][kk * 32 + kg * 8]);
#pragma unroll
    for (int nt = 0; nt < 8; ++nt) {
      const short8v bfrag =
          *reinterpret_cast<const short8v*>(&wt[nt * 16 + r16][kk * 32 + kg * 8]);
      acc[nt] = __builtin_amdgcn_mfma_f32_16x16x32_bf16(afrag, bfrag, acc[nt],
                                                        0, 0, 0);
    }
  }

#pragma unroll
  for (int nt = 0; nt < 8; ++nt) {
#pragma unroll
    for (int reg = 0; reg < 4; ++reg) {
      const float v = acc[nt][reg];
      const float vp = __shfl_xor(v, 1, 64);
      if (!(lane & 1)) {
        const int node = n0 + w * 16 + kg * 4 + reg;
        if (node < N_NODES) {
          const unsigned u = f2bf(v) | (f2bf(vp) << 16);
          xtb[(size_t)node * 64 + nt * 8 + (r16 >> 1)] = u;
        }
      }
    }
  }
}

// ---------------------------------------------------------------------------
// K2: dst histogram + alpha reduction from xtb.
// ---------------------------------------------------------------------------
__global__ __launch_bounds__(256) void k_hist_alpha(
    const int* __restrict__ ei, const unsigned* __restrict__ xtb,
    const float* __restrict__ a, unsigned* __restrict__ count,
    float* __restrict__ alpha_src, float* __restrict__ alpha_dst) {
  const int t = threadIdx.x;
  const int e = blockIdx.x * 256 + t;
  atomicAdd(&count[__builtin_nontemporal_load(&ei[N_EDGES + e])], 1u);

  const int node = blockIdx.x * 16 + (t >> 2);
  if (node >= N_NODES) return;
  const int q = t & 3;
  const unsigned* __restrict__ row = &xtb[(size_t)node * 64 + q * 16];
  const float* __restrict__ as = &a[q * 72];
  const float* __restrict__ ad = &a[q * 72 + 32];
  float s = 0.f, d = 0.f;
#pragma unroll
  for (int j = 0; j < 16; ++j) {
    const unsigned u = row[j];
    const float lo = __uint_as_float(u << 16);
    const float hi = __uint_as_float(u & 0xffff0000u);
    s = fmaf(lo, as[2 * j], s);
    s = fmaf(hi, as[2 * j + 1], s);
    d = fmaf(lo, ad[2 * j], d);
    d = fmaf(hi, ad[2 * j + 1], d);
  }
  alpha_src[node * 4 + q] = s;
  alpha_dst[node * 4 + q] = d;
}

// ---------------------------------------------------------------------------
// K3a/b/c: hierarchical exclusive scan; k_scan_c seeds bfill[b] = rs[b*512].
// ---------------------------------------------------------------------------
__global__ __launch_bounds__(SCAN_BLK) void k_scan_a(
    const unsigned* __restrict__ cnt, unsigned* __restrict__ rs,
    unsigned* __restrict__ bsum) {
  __shared__ unsigned wpre[16];
  const int t = threadIdx.x;
  const int i = blockIdx.x * SCAN_BLK + t;
  const int lane = t & 63;
  const int wid = t >> 6;
  unsigned v = (i < N_NODES) ? cnt[i] : 0u;
  unsigned incl = v;
#pragma unroll
  for (int off = 1; off < 64; off <<= 1) {
    unsigned n = __shfl_up(incl, off, 64);
    if (lane >= off) incl += n;
  }
  if (lane == 63) wpre[wid] = incl;
  __syncthreads();
  if (t < 16) {
    unsigned wv = wpre[t];
    unsigned wincl = wv;
#pragma unroll
    for (int off = 1; off < 16; off <<= 1) {
      unsigned n = __shfl_up(wincl, off, 64);
      if (t >= off) wincl += n;
    }
    wpre[t] = wincl - wv;
    if (t == 15) bsum[blockIdx.x] = wincl;
  }
  __syncthreads();
  if (i < N_NODES) rs[i] = incl - v + wpre[wid];
}

__global__ __launch_bounds__(64) void k_scan_b(unsigned* __restrict__ bsum,
                                               unsigned* __restrict__ boff) {
  const int t = threadIdx.x;
  unsigned v = (t < N_SCAN_BLKS) ? bsum[t] : 0u;
  unsigned incl = v;
#pragma unroll
  for (int off = 1; off < 64; off <<= 1) {
    unsigned n = __shfl_up(incl, off, 64);
    if (t >= off) incl += n;
  }
  if (t < N_SCAN_BLKS) boff[t] = incl - v;
}

__global__ __launch_bounds__(SCAN_BLK) void k_scan_c(
    unsigned* __restrict__ rs, const unsigned* __restrict__ boff,
    unsigned* __restrict__ bfill) {
  const int i = blockIdx.x * SCAN_BLK + threadIdx.x;
  if (i < N_NODES) {
    const unsigned v = rs[i] + boff[i >> 10];
    rs[i] = v;
    if ((i & 511) == 0) bfill[i >> 9] = v;   // bucket staging cursor
  }
  if (i == 0) rs[N_NODES] = N_EDGES;
}

// ---------------------------------------------------------------------------
// entry builder: {src, fp16x2(s0,s1), fp16x2(s2,s3), dst}
// ---------------------------------------------------------------------------
__device__ __forceinline__ uintx4 make_entry(
    int e, int src, int dst, const float* __restrict__ ea,
    const float* __restrict__ a, const float* __restrict__ alpha_src,
    const float* __restrict__ alpha_dst) {
  const floatx4 ev0 = __builtin_nontemporal_load(
      reinterpret_cast<const floatx4*>(&ea[(size_t)e * EDGE_DIM]));
  const floatx4 ev1 = __builtin_nontemporal_load(
      reinterpret_cast<const floatx4*>(&ea[(size_t)e * EDGE_DIM + 4]));
  const float4 als = *reinterpret_cast<const float4*>(&alpha_src[src * 4]);
  const float4 ald = *reinterpret_cast<const float4*>(&alpha_dst[dst * 4]);
  const float* alsp = reinterpret_cast<const float*>(&als);
  const float* aldp = reinterpret_cast<const float*>(&ald);
  unsigned sh[4];
#pragma unroll
  for (int h = 0; h < HEADS; ++h) {
    float s = alsp[h] + aldp[h];
    const float* ae = &a[h * 72 + 64];
    s = fmaf(ev0.x, ae[0], s);
    s = fmaf(ev0.y, ae[1], s);
    s = fmaf(ev0.z, ae[2], s);
    s = fmaf(ev0.w, ae[3], s);
    s = fmaf(ev1.x, ae[4], s);
    s = fmaf(ev1.y, ae[5], s);
    s = fmaf(ev1.z, ae[6], s);
    s = fmaf(ev1.w, ae[7], s);
    s = s > 0.f ? s : LRELU_ALPHA * s;
    sh[h] = (unsigned)__half_as_ushort(__float2half(s));
  }
  uintx4 ent;
  ent.x = (unsigned)src;
  ent.y = sh[0] | (sh[1] << 16);
  ent.z = sh[2] | (sh[3] << 16);
  ent.w = (unsigned)dst;
  return ent;
}

// ---------------------------------------------------------------------------
// K4a: bucket binsort — 1024 threads, EPT=2 (round-13 occupancy fix:
// was 256thr/EPT=8 → VGPR 136, 8.5% occupancy, latency-bound).
// ---------------------------------------------------------------------------
__global__ __launch_bounds__(BT) void k_binsort(
    const int* __restrict__ ei, const float* __restrict__ ea,
    const float* __restrict__ a, const float* __restrict__ alpha_src,
    const float* __restrict__ alpha_dst, unsigned* __restrict__ bfill,
    uintx4* __restrict__ stage) {
  __shared__ uintx4 sent[EPB];
  __shared__ unsigned short sbk[EPB];
  __shared__ unsigned lhist[128];
  __shared__ unsigned lscan[128];
  __shared__ unsigned gb[128];
  const int t = threadIdx.x;
  const int e0 = blockIdx.x * EPB;
  const int nvalid = min(EPB, N_EDGES - e0);

  if (t < 128) lhist[t] = 0u;
  __syncthreads();

  uintx4 ent[EPT];
  int bk[EPT];
  int lpos[EPT];
#pragma unroll
  for (int k = 0; k < EPT; ++k) {
    const int e = e0 + k * BT + t;
    bk[k] = -1;
    if (e < N_EDGES) {
      const int src = __builtin_nontemporal_load(&ei[e]);
      const int dst = __builtin_nontemporal_load(&ei[N_EDGES + e]);
      ent[k] = make_entry(e, src, dst, ea, a, alpha_src, alpha_dst);
      bk[k] = dst >> 9;
      lpos[k] = (int)atomicAdd(&lhist[bk[k]], 1u);
    }
  }
  __syncthreads();

  // inclusive Hillis-Steele scan of lhist over 128 slots
  if (t < 128) lscan[t] = lhist[t];
  __syncthreads();
#pragma unroll
  for (int off = 1; off < 128; off <<= 1) {
    unsigned v = 0u;
    if (t < 128 && t >= off) v = lscan[t - off];
    __syncthreads();
    if (t < 128) lscan[t] += v;
    __syncthreads();
  }
  // make exclusive + reserve global runs
  if (t < NBUCK) {
    const unsigned cnt = lhist[t];
    lscan[t] -= cnt;
    gb[t] = cnt ? atomicAdd(&bfill[t], cnt) : 0u;
  }
  __syncthreads();

  // reorder into LDS (bucket-sorted)
#pragma unroll
  for (int k = 0; k < EPT; ++k) {
    if (bk[k] >= 0) {
      const int p = (int)lscan[bk[k]] + lpos[k];
      sent[p] = ent[k];
      sbk[p] = (unsigned short)bk[k];
    }
  }
  __syncthreads();

  // coalesced run writes: consecutive p -> consecutive global addrs
#pragma unroll
  for (int k = 0; k < EPT; ++k) {
    const int p = k * BT + t;
    if (p < nvalid) {
      const int b = sbk[p];
      stage[gb[b] + (unsigned)(p - (int)lscan[b])] = sent[p];
    }
  }
}

// ---------------------------------------------------------------------------
// K4b: place. Block b owns bucket b; LDS fill counters; single-writer per
// bucket region -> full-line CSR writebacks.
// ---------------------------------------------------------------------------
__global__ __launch_bounds__(1024) void k_place(
    const unsigned* __restrict__ rs, const uintx4* __restrict__ stage,
    uintx4* __restrict__ csr) {
  __shared__ unsigned lfill[NODES_PER_BUCK];
  const int b = blockIdx.x;
  const int node0 = b << 9;
  const int nn = min(NODES_PER_BUCK, N_NODES - node0);
  const int t = threadIdx.x;
  if (t < nn) lfill[t] = rs[node0 + t];
  __syncthreads();
  const unsigned j0 = rs[node0];
  const unsigned j1 = rs[min(node0 + NODES_PER_BUCK, N_NODES)];
  for (unsigned i = j0 + t; i < j1; i += 1024) {
    const uintx4 ent = __builtin_nontemporal_load(&stage[i]);
    const int dst = (int)ent.w;
    const unsigned slot = atomicAdd(&lfill[dst - node0], 1u);
    csr[slot] = ent;
  }
}

// ---------------------------------------------------------------------------
// K5: one wave per dst; single-pass softmax, batched 16-wide gather.
// ---------------------------------------------------------------------------
__device__ __forceinline__ float ent_score(const uintx4& ent, int hA) {
  const unsigned uu = (hA < 2) ? ent.y : ent.z;
  const unsigned us = (hA & 1) ? (uu >> 16) : (uu & 0xffffu);
  return __half2float(__ushort_as_half((unsigned short)us));
}

__global__ __launch_bounds__(256) void k_agg(
    const unsigned* __restrict__ rs, const uintx4* __restrict__ csr,
    const unsigned* __restrict__ xtb, float* __restrict__ out) {
  const int lane = threadIdx.x & 63;
  const int dst = (int)((blockIdx.x * (unsigned)blockDim.x + threadIdx.x) >> 6);
  if (dst >= N_NODES) return;

  const unsigned j0 = rs[dst];
  const unsigned j1 = rs[dst + 1];
  const int deg = (int)(j1 - j0);

  float a0 = 0.f, a1 = 0.f, lsum = 0.f;

  if (deg > 0) {
    const int rounds = (deg + 15) >> 4;
    const int sub = lane >> 2;
    const int hA = lane & 3;
    const int hB = lane >> 4;

    for (int r = 0; r < rounds; ++r) {
      const int base = (int)j0 + r * 16;
      const int j = base + sub;
      uintx4 ent;
      if (j < (int)j1) {
        ent = __builtin_nontemporal_load(&csr[j]);
      } else {
        ent.x = 0u; ent.y = 0xfc00fc00u; ent.z = 0xfc00fc00u; ent.w = 0u;
      }
      const float w = __expf(ent_score(ent, hA));  // pad: exp(-inf)=0
      lsum += w;
      const int sx = (int)ent.x;
#pragma unroll
      for (int jj = 0; jj < 16; ++jj) {
        const int src = __shfl(sx, 4 * jj, 64);
        const float wj = __shfl(w, 4 * jj + hB, 64);
        const unsigned u = xtb[(size_t)src * 64 + lane];
        a0 = fmaf(wj, __uint_as_float(u << 16), a0);
        a1 = fmaf(wj, __uint_as_float(u & 0xffff0000u), a1);
      }
    }
    lsum += __shfl_xor(lsum, 4, 64);
    lsum += __shfl_xor(lsum, 8, 64);
    lsum += __shfl_xor(lsum, 16, 64);
    lsum += __shfl_xor(lsum, 32, 64);
    lsum = __shfl(lsum, hB, 64);
  }

  const float inv = 1.0f / (lsum + 1e-10f);
  out[(size_t)dst * 128 + lane * 2 + 0] = a0 * inv;
  out[(size_t)dst * 128 + lane * 2 + 1] = a1 * inv;
}

extern "C" void kernel_launch(void* const* d_in, const int* in_sizes, int n_in,
                              void* d_out, int out_size, void* d_ws,
                              size_t ws_size, hipStream_t stream) {
  const float* x = (const float*)d_in[0];
  const int* ei = (const int*)d_in[1];
  const float* ea = (const float*)d_in[2];
  const float* W = (const float*)d_in[3];
  const float* a = (const float*)d_in[4];
  float* out = (float*)d_out;

  // workspace layout
  char* p = (char*)d_ws;
  unsigned* xtb = (unsigned*)p;     p += (size_t)N_NODES * 64 * 4;    // 12.8 MB
  uintx4* csr = (uintx4*)p;         p += (size_t)N_EDGES * 16;        // 12.8 MB
  uintx4* stage = (uintx4*)p;       p += (size_t)N_EDGES * 16;        // 12.8 MB
  float* alpha_src = (float*)p;     p += (size_t)N_NODES * 4 * 4;     // 0.8 MB
  float* alpha_dst = (float*)p;     p += (size_t)N_NODES * 4 * 4;     // 0.8 MB
  unsigned* count = (unsigned*)p;   p += (size_t)N_NODES * 4;         // 0.2 MB
  unsigned* rs = (unsigned*)p;      p += (size_t)(N_NODES + 1) * 4;
  unsigned* bfill = (unsigned*)p;   p += 128 * 4;
  unsigned* bsum = (unsigned*)p;    p += 64 * 4;
  unsigned* boff = (unsigned*)p;    p += 64 * 4;

  (void)hipMemsetAsync(count, 0, (size_t)N_NODES * 4, stream);

  k_transform<<<(N_NODES + 63) / 64, 256, 0, stream>>>(x, W, xtb);
  k_hist_alpha<<<HIST_BLKS, 256, 0, stream>>>(ei, xtb, a, count, alpha_src,
                                              alpha_dst);
  k_scan_a<<<N_SCAN_BLKS, SCAN_BLK, 0, stream>>>(count, rs, bsum);
  k_scan_b<<<1, 64, 0, stream>>>(bsum, boff);
  k_scan_c<<<N_SCAN_BLKS, SCAN_BLK, 0, stream>>>(rs, boff, bfill);
  k_binsort<<<NBLK_A, BT, 0, stream>>>(ei, ea, a, alpha_src, alpha_dst, bfill,
                                       stage);
  k_place<<<NBUCK, 1024, 0, stream>>>(rs, stage, csr);
  k_agg<<<(N_NODES * 64 + 255) / 256, 256, 0, stream>>>(rs, csr, xtb, out);
}

// Round 14
// 113.969 us; speedup vs baseline: 1.4562x; 1.3157x over previous
//
#include <hip/hip_runtime.h>
#include <hip/hip_fp16.h>

#define N_NODES 50000
#define N_EDGES 800000
#define IN_F    128
#define OUT_F   32
#define HEADS   4
#define EDGE_DIM 8
#define LRELU_ALPHA 0.2f

#define EPB 2048                      // edges per binsort block
#define BT  1024                      // binsort threads
#define EPT (EPB / BT)                // 2 edges per thread
#define NBUCK 98                      // buckets of 512 nodes (dst>>9)
#define NBLK_A ((N_EDGES + EPB - 1) / EPB)  // 391
#define NODES_PER_BUCK 512
#define CAP 10240                     // staging capacity per bucket (avg 8163)

// native clang vector types
typedef float    floatx4 __attribute__((ext_vector_type(4)));
typedef unsigned uintx4  __attribute__((ext_vector_type(4)));
typedef short    short4v __attribute__((ext_vector_type(4)));
typedef short    short8v __attribute__((ext_vector_type(8)));
typedef float    f32x4   __attribute__((ext_vector_type(4)));

// round-to-nearest-even f32 -> bf16 (as ushort in low bits)
__device__ __forceinline__ unsigned f2bf(float f) {
  unsigned u = __float_as_uint(f);
  return (u + 0x7fffu + ((u >> 16) & 1u)) >> 16;
}

// ---------------------------------------------------------------------------
// K1: MFMA bf16 GEMM. xt[n,ho] = sum_i x[n,i]*W[h,i,o]; 64 nodes/block.
// ---------------------------------------------------------------------------
__global__ __launch_bounds__(256) void k_transform(
    const float* __restrict__ x, const float* __restrict__ W,
    unsigned* __restrict__ xtb) {
  __shared__ short sxb[64][136];
  __shared__ short wt[128][136];
  const int t = threadIdx.x;
  const int n0 = blockIdx.x * 64;

#pragma unroll
  for (int r = 0; r < 64; ++r) {
    const int idx = r * 256 + t;
    const int h = idx >> 12;
    const int i = (idx >> 5) & 127;
    const int o = idx & 31;
    wt[h * 32 + o][i] = (short)f2bf(W[idx]);
  }

#pragma unroll
  for (int r = 0; r < 8; ++r) {
    const int f = r * 256 + t;
    const int node = f >> 5;
    const int i4 = (f & 31) * 4;
    const int n = n0 + node;
    float4 v = make_float4(0.f, 0.f, 0.f, 0.f);
    if (n < N_NODES) v = *reinterpret_cast<const float4*>(&x[(size_t)n * 128 + i4]);
    short4v s4;
    s4.x = (short)f2bf(v.x);
    s4.y = (short)f2bf(v.y);
    s4.z = (short)f2bf(v.z);
    s4.w = (short)f2bf(v.w);
    *reinterpret_cast<short4v*>(&sxb[node][i4]) = s4;
  }
  __syncthreads();

  const int w = t >> 6;
  const int lane = t & 63;
  const int r16 = lane & 15;
  const int kg = lane >> 4;

  f32x4 acc[8];
#pragma unroll
  for (int nt = 0; nt < 8; ++nt) acc[nt] = (f32x4)(0.f);

#pragma unroll
  for (int kk = 0; kk < 4; ++kk) {
    const short8v afrag =
        *reinterpret_cast<const short8v*>(&sxb[w * 16 + r16][kk * 32 + kg * 8]);
#pragma unroll
    for (int nt = 0; nt < 8; ++nt) {
      const short8v bfrag =
          *reinterpret_cast<const short8v*>(&wt[nt * 16 + r16][kk * 32 + kg * 8]);
      acc[nt] = __builtin_amdgcn_mfma_f32_16x16x32_bf16(afrag, bfrag, acc[nt],
                                                        0, 0, 0);
    }
  }

#pragma unroll
  for (int nt = 0; nt < 8; ++nt) {
#pragma unroll
    for (int reg = 0; reg < 4; ++reg) {
      const float v = acc[nt][reg];
      const float vp = __shfl_xor(v, 1, 64);
      if (!(lane & 1)) {
        const int node = n0 + w * 16 + kg * 4 + reg;
        if (node < N_NODES) {
          const unsigned u = f2bf(v) | (f2bf(vp) << 16);
          xtb[(size_t)node * 64 + nt * 8 + (r16 >> 1)] = u;
        }
      }
    }
  }
}

// ---------------------------------------------------------------------------
// K2: alpha reduction from xtb (64 nodes/block, quad per node — fixed
// overlap bug from k_hist_alpha) + block 0 seeds bfill[b]=b*CAP.
// ---------------------------------------------------------------------------
__global__ __launch_bounds__(256) void k_alpha(
    const unsigned* __restrict__ xtb, const float* __restrict__ a,
    float* __restrict__ alpha_src, float* __restrict__ alpha_dst,
    unsigned* __restrict__ bfill) {
  const int t = threadIdx.x;
  if (blockIdx.x == 0 && t < NBUCK) bfill[t] = (unsigned)(t * CAP);

  const int node = blockIdx.x * 64 + (t >> 2);
  if (node >= N_NODES) return;
  const int q = t & 3;  // head
  const unsigned* __restrict__ row = &xtb[(size_t)node * 64 + q * 16];
  const float* __restrict__ as = &a[q * 72];
  const float* __restrict__ ad = &a[q * 72 + 32];
  float s = 0.f, d = 0.f;
#pragma unroll
  for (int j = 0; j < 16; ++j) {
    const unsigned u = row[j];
    const float lo = __uint_as_float(u << 16);
    const float hi = __uint_as_float(u & 0xffff0000u);
    s = fmaf(lo, as[2 * j], s);
    s = fmaf(hi, as[2 * j + 1], s);
    d = fmaf(lo, ad[2 * j], d);
    d = fmaf(hi, ad[2 * j + 1], d);
  }
  alpha_src[node * 4 + q] = s;
  alpha_dst[node * 4 + q] = d;
}

// ---------------------------------------------------------------------------
// entry builder: {src, fp16x2(s0,s1), fp16x2(s2,s3), dst}
// ---------------------------------------------------------------------------
__device__ __forceinline__ uintx4 make_entry(
    int e, int src, int dst, const float* __restrict__ ea,
    const float* __restrict__ a, const float* __restrict__ alpha_src,
    const float* __restrict__ alpha_dst) {
  const floatx4 ev0 = __builtin_nontemporal_load(
      reinterpret_cast<const floatx4*>(&ea[(size_t)e * EDGE_DIM]));
  const floatx4 ev1 = __builtin_nontemporal_load(
      reinterpret_cast<const floatx4*>(&ea[(size_t)e * EDGE_DIM + 4]));
  const float4 als = *reinterpret_cast<const float4*>(&alpha_src[src * 4]);
  const float4 ald = *reinterpret_cast<const float4*>(&alpha_dst[dst * 4]);
  const float* alsp = reinterpret_cast<const float*>(&als);
  const float* aldp = reinterpret_cast<const float*>(&ald);
  unsigned sh[4];
#pragma unroll
  for (int h = 0; h < HEADS; ++h) {
    float s = alsp[h] + aldp[h];
    const float* ae = &a[h * 72 + 64];
    s = fmaf(ev0.x, ae[0], s);
    s = fmaf(ev0.y, ae[1], s);
    s = fmaf(ev0.z, ae[2], s);
    s = fmaf(ev0.w, ae[3], s);
    s = fmaf(ev1.x, ae[4], s);
    s = fmaf(ev1.y, ae[5], s);
    s = fmaf(ev1.z, ae[6], s);
    s = fmaf(ev1.w, ae[7], s);
    s = s > 0.f ? s : LRELU_ALPHA * s;
    sh[h] = (unsigned)__half_as_ushort(__float2half(s));
  }
  uintx4 ent;
  ent.x = (unsigned)src;
  ent.y = sh[0] | (sh[1] << 16);
  ent.z = sh[2] | (sh[3] << 16);
  ent.w = (unsigned)dst;
  return ent;
}

// ---------------------------------------------------------------------------
// K3: bucket binsort into fixed-capacity regions (stage[b*CAP ...]).
// bfill[b] pre-seeded to b*CAP; cursor end - b*CAP = bucket count.
// ---------------------------------------------------------------------------
__global__ __launch_bounds__(BT) void k_binsort(
    const int* __restrict__ ei, const float* __restrict__ ea,
    const float* __restrict__ a, const float* __restrict__ alpha_src,
    const float* __restrict__ alpha_dst, unsigned* __restrict__ bfill,
    uintx4* __restrict__ stage) {
  __shared__ uintx4 sent[EPB];
  __shared__ unsigned short sbk[EPB];
  __shared__ unsigned lhist[128];
  __shared__ unsigned lscan[128];
  __shared__ unsigned gb[128];
  const int t = threadIdx.x;
  const int e0 = blockIdx.x * EPB;
  const int nvalid = min(EPB, N_EDGES - e0);

  if (t < 128) lhist[t] = 0u;
  __syncthreads();

  uintx4 ent[EPT];
  int bk[EPT];
  int lpos[EPT];
#pragma unroll
  for (int k = 0; k < EPT; ++k) {
    const int e = e0 + k * BT + t;
    bk[k] = -1;
    if (e < N_EDGES) {
      const int src = __builtin_nontemporal_load(&ei[e]);
      const int dst = __builtin_nontemporal_load(&ei[N_EDGES + e]);
      ent[k] = make_entry(e, src, dst, ea, a, alpha_src, alpha_dst);
      bk[k] = dst >> 9;
      lpos[k] = (int)atomicAdd(&lhist[bk[k]], 1u);
    }
  }
  __syncthreads();

  if (t < 128) lscan[t] = lhist[t];
  __syncthreads();
#pragma unroll
  for (int off = 1; off < 128; off <<= 1) {
    unsigned v = 0u;
    if (t < 128 && t >= off) v = lscan[t - off];
    __syncthreads();
    if (t < 128) lscan[t] += v;
    __syncthreads();
  }
  if (t < NBUCK) {
    const unsigned cnt = lhist[t];
    lscan[t] -= cnt;
    gb[t] = cnt ? atomicAdd(&bfill[t], cnt) : 0u;
  }
  __syncthreads();

#pragma unroll
  for (int k = 0; k < EPT; ++k) {
    if (bk[k] >= 0) {
      const int p = (int)lscan[bk[k]] + lpos[k];
      sent[p] = ent[k];
      sbk[p] = (unsigned short)bk[k];
    }
  }
  __syncthreads();

#pragma unroll
  for (int k = 0; k < EPT; ++k) {
    const int p = k * BT + t;
    if (p < nvalid) {
      const int b = sbk[p];
      stage[gb[b] + (unsigned)(p - (int)lscan[b])] = sent[p];
    }
  }
}

// ---------------------------------------------------------------------------
// K4: tiny scan over 98 bucket counts -> bstart (exclusive CSR bucket starts)
// ---------------------------------------------------------------------------
__global__ __launch_bounds__(128) void k_scan_s(
    const unsigned* __restrict__ bfill, unsigned* __restrict__ bstart) {
  __shared__ unsigned s[128];
  const int t = threadIdx.x;
  const unsigned cnt = (t < NBUCK) ? (bfill[t] - (unsigned)(t * CAP)) : 0u;
  s[t] = cnt;
  __syncthreads();
#pragma unroll
  for (int off = 1; off < 128; off <<= 1) {
    unsigned v = (t >= off) ? s[t - off] : 0u;
    __syncthreads();
    s[t] += v;
    __syncthreads();
  }
  if (t < NBUCK) bstart[t] = s[t] - cnt;
  if (t == 0) bstart[NBUCK] = N_EDGES;
}

// ---------------------------------------------------------------------------
// K5: place. Block b owns bucket b. Pass 1: LDS per-node counts from staged
// entries -> block scan -> write rs + seed LDS cursors. Pass 2: place into
// CSR (single-writer 128KB region -> full-line writebacks).
// ---------------------------------------------------------------------------
__global__ __launch_bounds__(1024) void k_place(
    const unsigned* __restrict__ bfill, const unsigned* __restrict__ bstart,
    const uintx4* __restrict__ stage, unsigned* __restrict__ rs,
    uintx4* __restrict__ csr) {
  __shared__ unsigned lbuf[NODES_PER_BUCK];
  __shared__ unsigned wsum[8];
  const int b = blockIdx.x;
  const int t = threadIdx.x;
  const int node0 = b << 9;
  const int nn = min(NODES_PER_BUCK, N_NODES - node0);
  const unsigned base = (unsigned)(b * CAP);
  const unsigned cnt = bfill[b] - base;
  const unsigned bs = bstart[b];

  if (t < NODES_PER_BUCK) lbuf[t] = 0u;
  __syncthreads();

  // pass 1: per-node counts
  for (unsigned i = t; i < cnt; i += 1024) {
    const unsigned dst = __builtin_nontemporal_load(&stage[base + i]).w;
    atomicAdd(&lbuf[dst - (unsigned)node0], 1u);
  }
  __syncthreads();

  // block scan of 512 counts (8 waves)
  const unsigned c = (t < NODES_PER_BUCK) ? lbuf[t] : 0u;
  unsigned incl = c;
  const int lane = t & 63;
#pragma unroll
  for (int off = 1; off < 64; off <<= 1) {
    const unsigned n = __shfl_up(incl, off, 64);
    if (lane >= off) incl += n;
  }
  if (t < NODES_PER_BUCK && lane == 63) wsum[t >> 6] = incl;
  __syncthreads();
  if (t < 8) {
    const unsigned wv = wsum[t];
    unsigned wincl = wv;
#pragma unroll
    for (int off = 1; off < 8; off <<= 1) {
      const unsigned n = __shfl_up(wincl, off, 64);
      if (t >= off) wincl += n;
    }
    wsum[t] = wincl - wv;  // exclusive wave prefix
  }
  __syncthreads();
  if (t < NODES_PER_BUCK) {
    const unsigned excl = incl - c + wsum[t >> 6];
    lbuf[t] = bs + excl;             // cursor
    if (t < nn) rs[node0 + t] = bs + excl;
  }
  if (b == NBUCK - 1 && t == 0) rs[N_NODES] = N_EDGES;
  __syncthreads();

  // pass 2: place
  for (unsigned i = t; i < cnt; i += 1024) {
    const uintx4 ent = __builtin_nontemporal_load(&stage[base + i]);
    const unsigned slot = atomicAdd(&lbuf[ent.w - (unsigned)node0], 1u);
    csr[slot] = ent;
  }
}

// ---------------------------------------------------------------------------
// K6: one wave per dst; single-pass softmax, batched 16-wide gather.
// ---------------------------------------------------------------------------
__device__ __forceinline__ float ent_score(const uintx4& ent, int hA) {
  const unsigned uu = (hA < 2) ? ent.y : ent.z;
  const unsigned us = (hA & 1) ? (uu >> 16) : (uu & 0xffffu);
  return __half2float(__ushort_as_half((unsigned short)us));
}

__global__ __launch_bounds__(256) void k_agg(
    const unsigned* __restrict__ rs, const uintx4* __restrict__ csr,
    const unsigned* __restrict__ xtb, float* __restrict__ out) {
  const int lane = threadIdx.x & 63;
  const int dst = (int)((blockIdx.x * (unsigned)blockDim.x + threadIdx.x) >> 6);
  if (dst >= N_NODES) return;

  const unsigned j0 = rs[dst];
  const unsigned j1 = rs[dst + 1];
  const int deg = (int)(j1 - j0);

  float a0 = 0.f, a1 = 0.f, lsum = 0.f;

  if (deg > 0) {
    const int rounds = (deg + 15) >> 4;
    const int sub = lane >> 2;
    const int hA = lane & 3;
    const int hB = lane >> 4;

    for (int r = 0; r < rounds; ++r) {
      const int base = (int)j0 + r * 16;
      const int j = base + sub;
      uintx4 ent;
      if (j < (int)j1) {
        ent = __builtin_nontemporal_load(&csr[j]);
      } else {
        ent.x = 0u; ent.y = 0xfc00fc00u; ent.z = 0xfc00fc00u; ent.w = 0u;
      }
      const float w = __expf(ent_score(ent, hA));  // pad: exp(-inf)=0
      lsum += w;
      const int sx = (int)ent.x;
#pragma unroll
      for (int jj = 0; jj < 16; ++jj) {
        const int src = __shfl(sx, 4 * jj, 64);
        const float wj = __shfl(w, 4 * jj + hB, 64);
        const unsigned u = xtb[(size_t)src * 64 + lane];
        a0 = fmaf(wj, __uint_as_float(u << 16), a0);
        a1 = fmaf(wj, __uint_as_float(u & 0xffff0000u), a1);
      }
    }
    lsum += __shfl_xor(lsum, 4, 64);
    lsum += __shfl_xor(lsum, 8, 64);
    lsum += __shfl_xor(lsum, 16, 64);
    lsum += __shfl_xor(lsum, 32, 64);
    lsum = __shfl(lsum, hB, 64);
  }

  const float inv = 1.0f / (lsum + 1e-10f);
  out[(size_t)dst * 128 + lane * 2 + 0] = a0 * inv;
  out[(size_t)dst * 128 + lane * 2 + 1] = a1 * inv;
}

extern "C" void kernel_launch(void* const* d_in, const int* in_sizes, int n_in,
                              void* d_out, int out_size, void* d_ws,
                              size_t ws_size, hipStream_t stream) {
  const float* x = (const float*)d_in[0];
  const int* ei = (const int*)d_in[1];
  const float* ea = (const float*)d_in[2];
  const float* W = (const float*)d_in[3];
  const float* a = (const float*)d_in[4];
  float* out = (float*)d_out;

  // workspace layout
  char* p = (char*)d_ws;
  unsigned* xtb = (unsigned*)p;     p += (size_t)N_NODES * 64 * 4;      // 12.8 MB
  uintx4* csr = (uintx4*)p;         p += (size_t)N_EDGES * 16;          // 12.8 MB
  uintx4* stage = (uintx4*)p;       p += (size_t)NBUCK * CAP * 16;      // 16.1 MB
  float* alpha_src = (float*)p;     p += (size_t)N_NODES * 4 * 4;       // 0.8 MB
  float* alpha_dst = (float*)p;     p += (size_t)N_NODES * 4 * 4;       // 0.8 MB
  unsigned* rs = (unsigned*)p;      p += (size_t)(N_NODES + 1) * 4;     // 0.2 MB
  unsigned* bfill = (unsigned*)p;   p += 128 * 4;
  unsigned* bstart = (unsigned*)p;  p += 128 * 4;

  k_transform<<<(N_NODES + 63) / 64, 256, 0, stream>>>(x, W, xtb);
  k_alpha<<<(N_NODES + 63) / 64, 256, 0, stream>>>(xtb, a, alpha_src,
                                                   alpha_dst, bfill);
  k_binsort<<<NBLK_A, BT, 0, stream>>>(ei, ea, a, alpha_src, alpha_dst, bfill,
                                       stage);
  k_scan_s<<<1, 128, 0, stream>>>(bfill, bstart);
  k_place<<<NBUCK, 1024, 0, stream>>>(bfill, bstart, stage, rs, csr);
  k_agg<<<(N_NODES * 64 + 255) / 256, 256, 0, stream>>>(rs, csr, xtb, out);
}

// Round 15
// 113.815 us; speedup vs baseline: 1.4582x; 1.0014x over previous
//
#include <hip/hip_runtime.h>
#include <hip/hip_fp16.h>

#define N_NODES 50000
#define N_EDGES 800000
#define IN_F    128
#define OUT_F   32
#define HEADS   4
#define EDGE_DIM 8
#define LRELU_ALPHA 0.2f

#define EPB 2048                      // edges per binsort block
#define BT  1024                      // binsort threads
#define EPT (EPB / BT)                // 2 edges per thread
#define NBUCK 98                      // buckets of 512 nodes (dst>>9)
#define NBLK_A ((N_EDGES + EPB - 1) / EPB)  // 391
#define NODES_PER_BUCK 512
#define CAP 10240                     // staging capacity per bucket (avg 8163)

// native clang vector types
typedef float    floatx4 __attribute__((ext_vector_type(4)));
typedef unsigned uintx4  __attribute__((ext_vector_type(4)));
typedef short    short4v __attribute__((ext_vector_type(4)));
typedef short    short8v __attribute__((ext_vector_type(8)));
typedef float    f32x4   __attribute__((ext_vector_type(4)));

// round-to-nearest-even f32 -> bf16 (as ushort in low bits)
__device__ __forceinline__ unsigned f2bf(float f) {
  unsigned u = __float_as_uint(f);
  return (u + 0x7fffu + ((u >> 16) & 1u)) >> 16;
}

// ---------------------------------------------------------------------------
// K1: MFMA bf16 GEMM + fused alpha reduction (from fp32 accumulators) +
// bfill seeding (block 0). 64 nodes/block.
// C/D layout (16x16x32 bf16): col=lane&15, row=(lane>>4)*4+reg.
// ---------------------------------------------------------------------------
__global__ __launch_bounds__(256) void k_transform(
    const float* __restrict__ x, const float* __restrict__ W,
    const float* __restrict__ a, unsigned* __restrict__ xtb,
    float* __restrict__ alpha_src, float* __restrict__ alpha_dst,
    unsigned* __restrict__ bfill) {
  __shared__ short sxb[64][136];
  __shared__ short wt[128][136];
  const int t = threadIdx.x;
  const int n0 = blockIdx.x * 64;

  if (blockIdx.x == 0 && t < NBUCK) bfill[t] = (unsigned)(t * CAP);

#pragma unroll
  for (int r = 0; r < 64; ++r) {
    const int idx = r * 256 + t;
    const int h = idx >> 12;
    const int i = (idx >> 5) & 127;
    const int o = idx & 31;
    wt[h * 32 + o][i] = (short)f2bf(W[idx]);
  }

#pragma unroll
  for (int r = 0; r < 8; ++r) {
    const int f = r * 256 + t;
    const int node = f >> 5;
    const int i4 = (f & 31) * 4;
    const int n = n0 + node;
    float4 v = make_float4(0.f, 0.f, 0.f, 0.f);
    if (n < N_NODES) v = *reinterpret_cast<const float4*>(&x[(size_t)n * 128 + i4]);
    short4v s4;
    s4.x = (short)f2bf(v.x);
    s4.y = (short)f2bf(v.y);
    s4.z = (short)f2bf(v.z);
    s4.w = (short)f2bf(v.w);
    *reinterpret_cast<short4v*>(&sxb[node][i4]) = s4;
  }
  __syncthreads();

  const int w = t >> 6;
  const int lane = t & 63;
  const int r16 = lane & 15;
  const int kg = lane >> 4;

  f32x4 acc[8];
#pragma unroll
  for (int nt = 0; nt < 8; ++nt) acc[nt] = (f32x4)(0.f);

#pragma unroll
  for (int kk = 0; kk < 4; ++kk) {
    const short8v afrag =
        *reinterpret_cast<const short8v*>(&sxb[w * 16 + r16][kk * 32 + kg * 8]);
#pragma unroll
    for (int nt = 0; nt < 8; ++nt) {
      const short8v bfrag =
          *reinterpret_cast<const short8v*>(&wt[nt * 16 + r16][kk * 32 + kg * 8]);
      acc[nt] = __builtin_amdgcn_mfma_f32_16x16x32_bf16(afrag, bfrag, acc[nt],
                                                        0, 0, 0);
    }
  }

  // store xt as packed bf16
#pragma unroll
  for (int nt = 0; nt < 8; ++nt) {
#pragma unroll
    for (int reg = 0; reg < 4; ++reg) {
      const float v = acc[nt][reg];
      const float vp = __shfl_xor(v, 1, 64);
      if (!(lane & 1)) {
        const int node = n0 + w * 16 + kg * 4 + reg;
        if (node < N_NODES) {
          const unsigned u = f2bf(v) | (f2bf(vp) << 16);
          xtb[(size_t)node * 64 + nt * 8 + (r16 >> 1)] = u;
        }
      }
    }
  }

  // fused alpha: column nt*16+r16 belongs to head nt>>1, o=(nt&1)*16+r16
  float asv[8], adv[8];
#pragma unroll
  for (int nt = 0; nt < 8; ++nt) {
    const int h = nt >> 1;
    const int o = (nt & 1) * 16 + r16;
    asv[nt] = a[h * 72 + o];
    adv[nt] = a[h * 72 + 32 + o];
  }
#pragma unroll
  for (int reg = 0; reg < 4; ++reg) {
    const int node = n0 + w * 16 + kg * 4 + reg;
    float s[4], d[4];
#pragma unroll
    for (int h = 0; h < 4; ++h) {
      s[h] = acc[2 * h][reg] * asv[2 * h] + acc[2 * h + 1][reg] * asv[2 * h + 1];
      d[h] = acc[2 * h][reg] * adv[2 * h] + acc[2 * h + 1][reg] * adv[2 * h + 1];
#pragma unroll
      for (int off = 1; off < 16; off <<= 1) {
        s[h] += __shfl_xor(s[h], off, 64);
        d[h] += __shfl_xor(d[h], off, 64);
      }
    }
    if (r16 < 4 && node < N_NODES) {
      const float sv = (r16 == 0) ? s[0] : (r16 == 1) ? s[1] : (r16 == 2) ? s[2] : s[3];
      const float dv = (r16 == 0) ? d[0] : (r16 == 1) ? d[1] : (r16 == 2) ? d[2] : d[3];
      alpha_src[node * 4 + r16] = sv;
      alpha_dst[node * 4 + r16] = dv;
    }
  }
}

// ---------------------------------------------------------------------------
// entry builder: {src, fp16x2(s0,s1), fp16x2(s2,s3), dst}
// ---------------------------------------------------------------------------
__device__ __forceinline__ uintx4 make_entry(
    int e, int src, int dst, const float* __restrict__ ea,
    const float* __restrict__ a, const float* __restrict__ alpha_src,
    const float* __restrict__ alpha_dst) {
  const floatx4 ev0 = __builtin_nontemporal_load(
      reinterpret_cast<const floatx4*>(&ea[(size_t)e * EDGE_DIM]));
  const floatx4 ev1 = __builtin_nontemporal_load(
      reinterpret_cast<const floatx4*>(&ea[(size_t)e * EDGE_DIM + 4]));
  const float4 als = *reinterpret_cast<const float4*>(&alpha_src[src * 4]);
  const float4 ald = *reinterpret_cast<const float4*>(&alpha_dst[dst * 4]);
  const float* alsp = reinterpret_cast<const float*>(&als);
  const float* aldp = reinterpret_cast<const float*>(&ald);
  unsigned sh[4];
#pragma unroll
  for (int h = 0; h < HEADS; ++h) {
    float s = alsp[h] + aldp[h];
    const float* ae = &a[h * 72 + 64];
    s = fmaf(ev0.x, ae[0], s);
    s = fmaf(ev0.y, ae[1], s);
    s = fmaf(ev0.z, ae[2], s);
    s = fmaf(ev0.w, ae[3], s);
    s = fmaf(ev1.x, ae[4], s);
    s = fmaf(ev1.y, ae[5], s);
    s = fmaf(ev1.z, ae[6], s);
    s = fmaf(ev1.w, ae[7], s);
    s = s > 0.f ? s : LRELU_ALPHA * s;
    sh[h] = (unsigned)__half_as_ushort(__float2half(s));
  }
  uintx4 ent;
  ent.x = (unsigned)src;
  ent.y = sh[0] | (sh[1] << 16);
  ent.z = sh[2] | (sh[3] << 16);
  ent.w = (unsigned)dst;
  return ent;
}

// ---------------------------------------------------------------------------
// K2: bucket binsort into fixed-capacity staging regions.
// ---------------------------------------------------------------------------
__global__ __launch_bounds__(BT) void k_binsort(
    const int* __restrict__ ei, const float* __restrict__ ea,
    const float* __restrict__ a, const float* __restrict__ alpha_src,
    const float* __restrict__ alpha_dst, unsigned* __restrict__ bfill,
    uintx4* __restrict__ stage) {
  __shared__ uintx4 sent[EPB];
  __shared__ unsigned short sbk[EPB];
  __shared__ unsigned lhist[128];
  __shared__ unsigned lscan[128];
  __shared__ unsigned gb[128];
  const int t = threadIdx.x;
  const int e0 = blockIdx.x * EPB;
  const int nvalid = min(EPB, N_EDGES - e0);

  if (t < 128) lhist[t] = 0u;
  __syncthreads();

  uintx4 ent[EPT];
  int bk[EPT];
  int lpos[EPT];
#pragma unroll
  for (int k = 0; k < EPT; ++k) {
    const int e = e0 + k * BT + t;
    bk[k] = -1;
    if (e < N_EDGES) {
      const int src = __builtin_nontemporal_load(&ei[e]);
      const int dst = __builtin_nontemporal_load(&ei[N_EDGES + e]);
      ent[k] = make_entry(e, src, dst, ea, a, alpha_src, alpha_dst);
      bk[k] = dst >> 9;
      lpos[k] = (int)atomicAdd(&lhist[bk[k]], 1u);
    }
  }
  __syncthreads();

  if (t < 128) lscan[t] = lhist[t];
  __syncthreads();
#pragma unroll
  for (int off = 1; off < 128; off <<= 1) {
    unsigned v = 0u;
    if (t < 128 && t >= off) v = lscan[t - off];
    __syncthreads();
    if (t < 128) lscan[t] += v;
    __syncthreads();
  }
  if (t < NBUCK) {
    const unsigned cnt = lhist[t];
    lscan[t] -= cnt;
    gb[t] = cnt ? atomicAdd(&bfill[t], cnt) : 0u;
  }
  __syncthreads();

#pragma unroll
  for (int k = 0; k < EPT; ++k) {
    if (bk[k] >= 0) {
      const int p = (int)lscan[bk[k]] + lpos[k];
      sent[p] = ent[k];
      sbk[p] = (unsigned short)bk[k];
    }
  }
  __syncthreads();

#pragma unroll
  for (int k = 0; k < EPT; ++k) {
    const int p = k * BT + t;
    if (p < nvalid) {
      const int b = sbk[p];
      stage[gb[b] + (unsigned)(p - (int)lscan[b])] = sent[p];
    }
  }
}

// ---------------------------------------------------------------------------
// K3: place (scan_s fused: every block scans the 98 bucket counts in LDS).
// Pass 1: per-node counts -> block scan -> rs + LDS cursors. Pass 2: place.
// ---------------------------------------------------------------------------
__global__ __launch_bounds__(1024) void k_place(
    const unsigned* __restrict__ bfill, const uintx4* __restrict__ stage,
    unsigned* __restrict__ rs, uintx4* __restrict__ csr) {
  __shared__ unsigned lbuf[NODES_PER_BUCK];
  __shared__ unsigned wsum[8];
  __shared__ unsigned bscan[128];
  const int b = blockIdx.x;
  const int t = threadIdx.x;
  const int node0 = b << 9;
  const int nn = min(NODES_PER_BUCK, N_NODES - node0);
  const unsigned base = (unsigned)(b * CAP);

  // fused bucket-start scan (98 counts)
  unsigned myc = 0u;
  if (t < 128) {
    myc = (t < NBUCK) ? (bfill[t] - (unsigned)(t * CAP)) : 0u;
    bscan[t] = myc;
  }
  __syncthreads();
#pragma unroll
  for (int off = 1; off < 128; off <<= 1) {
    unsigned v = 0u;
    if (t < 128 && t >= off) v = bscan[t - off];
    __syncthreads();
    if (t < 128) bscan[t] += v;
    __syncthreads();
  }
  if (t < 128 && t == b) bscan[127] = bscan[t] - myc;  // stash excl[b] at 127?
  // simpler: all threads read excl for b below
  __syncthreads();
  const unsigned cnt = bfill[b] - base;
  const unsigned bs = (b == 0) ? 0u : bscan[b - 1];

  if (t < NODES_PER_BUCK) lbuf[t] = 0u;
  __syncthreads();

  // pass 1: per-node counts
  for (unsigned i = t; i < cnt; i += 1024) {
    const unsigned dst = __builtin_nontemporal_load(&stage[base + i]).w;
    atomicAdd(&lbuf[dst - (unsigned)node0], 1u);
  }
  __syncthreads();

  // block scan of 512 counts (8 waves)
  const unsigned c = (t < NODES_PER_BUCK) ? lbuf[t] : 0u;
  unsigned incl = c;
  const int lane = t & 63;
#pragma unroll
  for (int off = 1; off < 64; off <<= 1) {
    const unsigned n = __shfl_up(incl, off, 64);
    if (lane >= off) incl += n;
  }
  if (t < NODES_PER_BUCK && lane == 63) wsum[t >> 6] = incl;
  __syncthreads();
  if (t < 8) {
    const unsigned wv = wsum[t];
    unsigned wincl = wv;
#pragma unroll
    for (int off = 1; off < 8; off <<= 1) {
      const unsigned n = __shfl_up(wincl, off, 64);
      if (t >= off) wincl += n;
    }
    wsum[t] = wincl - wv;
  }
  __syncthreads();
  if (t < NODES_PER_BUCK) {
    const unsigned excl = incl - c + wsum[t >> 6];
    lbuf[t] = bs + excl;
    if (t < nn) rs[node0 + t] = bs + excl;
  }
  if (b == NBUCK - 1 && t == 0) rs[N_NODES] = N_EDGES;
  __syncthreads();

  // pass 2: place
  for (unsigned i = t; i < cnt; i += 1024) {
    const uintx4 ent = __builtin_nontemporal_load(&stage[base + i]);
    const unsigned slot = atomicAdd(&lbuf[ent.w - (unsigned)node0], 1u);
    csr[slot] = ent;
  }
}

// ---------------------------------------------------------------------------
// K4: agg. One wave per dst; single-pass softmax; 2-round software pipeline
// (both csr loads issued before gathers; skip of 2nd round is wave-uniform).
// NT store for out.
// ---------------------------------------------------------------------------
__device__ __forceinline__ float ent_score(const uintx4& ent, int hA) {
  const unsigned uu = (hA < 2) ? ent.y : ent.z;
  const unsigned us = (hA & 1) ? (uu >> 16) : (uu & 0xffffu);
  return __half2float(__ushort_as_half((unsigned short)us));
}

__global__ __launch_bounds__(256) void k_agg(
    const unsigned* __restrict__ rs, const uintx4* __restrict__ csr,
    const unsigned* __restrict__ xtb, float* __restrict__ out) {
  const int lane = threadIdx.x & 63;
  const int dst = (int)((blockIdx.x * (unsigned)blockDim.x + threadIdx.x) >> 6);
  if (dst >= N_NODES) return;

  const unsigned j0 = rs[dst];
  const unsigned j1 = rs[dst + 1];
  const int deg = (int)(j1 - j0);

  float a0 = 0.f, a1 = 0.f, lsum = 0.f;

  if (deg > 0) {
    const int rounds = (deg + 15) >> 4;
    const int sub = lane >> 2;
    const int hA = lane & 3;
    const int hB = lane >> 4;

    const uintx4 pad = {0u, 0xfc00fc00u, 0xfc00fc00u, 0u};

    for (int r = 0; r < rounds; r += 2) {
      const int base0 = (int)j0 + r * 16;
      const int jA = base0 + sub;
      const int jB = base0 + 16 + sub;
      const bool has1 = (r + 1) < rounds;   // wave-uniform
      // issue both loads before any gather
      const uintx4 entA = (jA < (int)j1) ? __builtin_nontemporal_load(&csr[jA]) : pad;
      const uintx4 entB =
          (has1 && jB < (int)j1) ? __builtin_nontemporal_load(&csr[jB]) : pad;

      {
        const float w = __expf(ent_score(entA, hA));
        lsum += w;
        const int sx = (int)entA.x;
#pragma unroll
        for (int jj = 0; jj < 16; ++jj) {
          const int src = __shfl(sx, 4 * jj, 64);
          const float wj = __shfl(w, 4 * jj + hB, 64);
          const unsigned u = xtb[(size_t)src * 64 + lane];
          a0 = fmaf(wj, __uint_as_float(u << 16), a0);
          a1 = fmaf(wj, __uint_as_float(u & 0xffff0000u), a1);
        }
      }
      if (has1) {
        const float w = __expf(ent_score(entB, hA));
        lsum += w;
        const int sx = (int)entB.x;
#pragma unroll
        for (int jj = 0; jj < 16; ++jj) {
          const int src = __shfl(sx, 4 * jj, 64);
          const float wj = __shfl(w, 4 * jj + hB, 64);
          const unsigned u = xtb[(size_t)src * 64 + lane];
          a0 = fmaf(wj, __uint_as_float(u << 16), a0);
          a1 = fmaf(wj, __uint_as_float(u & 0xffff0000u), a1);
        }
      }
    }
    lsum += __shfl_xor(lsum, 4, 64);
    lsum += __shfl_xor(lsum, 8, 64);
    lsum += __shfl_xor(lsum, 16, 64);
    lsum += __shfl_xor(lsum, 32, 64);
    lsum = __shfl(lsum, hB, 64);
  }

  const float inv = 1.0f / (lsum + 1e-10f);
  floatx4 o;
  o.x = a0 * inv;
  o.y = a1 * inv;
  // pack pairs: even lanes hold (2l,2l+1); write float2 via NT 8B? Use scalar NT:
  __builtin_nontemporal_store(o.x, &out[(size_t)dst * 128 + lane * 2 + 0]);
  __builtin_nontemporal_store(o.y, &out[(size_t)dst * 128 + lane * 2 + 1]);
}

extern "C" void kernel_launch(void* const* d_in, const int* in_sizes, int n_in,
                              void* d_out, int out_size, void* d_ws,
                              size_t ws_size, hipStream_t stream) {
  const float* x = (const float*)d_in[0];
  const int* ei = (const int*)d_in[1];
  const float* ea = (const float*)d_in[2];
  const float* W = (const float*)d_in[3];
  const float* a = (const float*)d_in[4];
  float* out = (float*)d_out;

  // workspace layout
  char* p = (char*)d_ws;
  unsigned* xtb = (unsigned*)p;     p += (size_t)N_NODES * 64 * 4;      // 12.8 MB
  uintx4* csr = (uintx4*)p;         p += (size_t)N_EDGES * 16;          // 12.8 MB
  uintx4* stage = (uintx4*)p;       p += (size_t)NBUCK * CAP * 16;      // 16.1 MB
  float* alpha_src = (float*)p;     p += (size_t)N_NODES * 4 * 4;       // 0.8 MB
  float* alpha_dst = (float*)p;     p += (size_t)N_NODES * 4 * 4;       // 0.8 MB
  unsigned* rs = (unsigned*)p;      p += (size_t)(N_NODES + 1) * 4;     // 0.2 MB
  unsigned* bfill = (unsigned*)p;   p += 128 * 4;

  k_transform<<<(N_NODES + 63) / 64, 256, 0, stream>>>(x, W, a, xtb, alpha_src,
                                                       alpha_dst, bfill);
  k_binsort<<<NBLK_A, BT, 0, stream>>>(ei, ea, a, alpha_src, alpha_dst, bfill,
                                       stage);
  k_place<<<NBUCK, 1024, 0, stream>>>(bfill, stage, rs, csr);
  k_agg<<<(N_NODES * 64 + 255) / 256, 256, 0, stream>>>(rs, csr, xtb, out);
}